// Round 1
// baseline (9177.070 us; speedup 1.0000x reference)
//
#include <hip/hip_runtime.h>
#include <hip/hip_bf16.h>

// Problem dims (compile-time constants)
// B=512, S=64, IN=128, DM=256, H=8, HD=32, L=2, FF=1024, DO=64, E=8, K=2, GI=8192

#define DEVINL __device__ __forceinline__

DEVINL float b2f(unsigned short u) {
    unsigned int i = ((unsigned int)u) << 16;
    float f; __builtin_memcpy(&f, &i, 4); return f;
}
DEVINL unsigned short f2b(float f) {
    unsigned int i; __builtin_memcpy(&i, &f, 4);
    unsigned int r = (i + 0x7FFFu + ((i >> 16) & 1u)) >> 16;  // RTN-even
    return (unsigned short)r;
}

// ---------------------------------------------------------------------------
// K0: zero routing counters
__global__ void zero_cnt_kernel(int* __restrict__ cnt) {
    if (threadIdx.x < 8) cnt[threadIdx.x] = 0;
}

// ---------------------------------------------------------------------------
// K1: gate — logits in double (stable top-2 vs numpy ref), softmax of top-2,
// scatter (b, weight) into per-expert lists via atomics.
__global__ __launch_bounds__(256) void gate_kernel(
    const float* __restrict__ x, const float* __restrict__ Wg, const float* __restrict__ bg,
    int* __restrict__ cnt, int* __restrict__ rlist, float* __restrict__ wlist)
{
    const int b = blockIdx.x;
    const int tid = threadIdx.x;
    const int e8 = tid & 7;
    const int seg = tid >> 3;                 // 0..31
    const float* gi = x + (size_t)b * 8192;
    double p = 0.0;
    for (int ii = 0; ii < 256; ++ii) {
        int i = seg * 256 + ii;
        p += (double)gi[i] * (double)Wg[i * 8 + e8];
    }
    // combine segments with same e8 inside the wave (lane bits 3..5)
    p += __shfl_xor(p, 8, 64);
    p += __shfl_xor(p, 16, 64);
    p += __shfl_xor(p, 32, 64);
    __shared__ double wred[4 * 8];
    const int lane = tid & 63, w = tid >> 6;
    if (lane < 8) wred[w * 8 + lane] = p;
    __syncthreads();
    if (tid == 0) {
        double lg[8];
        for (int e = 0; e < 8; ++e)
            lg[e] = wred[e] + wred[8 + e] + wred[16 + e] + wred[24 + e] + (double)bg[e];
        int i1 = 0;
        for (int e = 1; e < 8; ++e) if (lg[e] > lg[i1]) i1 = e;   // first-max wins (ties)
        int i2 = (i1 == 0) ? 1 : 0;
        for (int e = 0; e < 8; ++e) if (e != i1 && lg[e] > lg[i2]) i2 = e;
        double ex = exp(lg[i2] - lg[i1]);     // <= 1
        float w1 = (float)(1.0 / (1.0 + ex));
        float w2 = (float)(ex / (1.0 + ex));
        int p1 = atomicAdd(&cnt[i1], 1);
        rlist[i1 * 512 + p1] = b; wlist[i1 * 512 + p1] = w1;
        int p2 = atomicAdd(&cnt[i2], 1);
        rlist[i2 * 512 + p2] = b; wlist[i2 * 512 + p2] = w2;
    }
}

// ---------------------------------------------------------------------------
// K2: residual projection — acc_out[b,d] = 0.1*(gi . Wr[:,d] + br[d])
// (initializes the combine accumulator; experts atomicAdd on top of it)
__global__ __launch_bounds__(256) void resproj_kernel(
    const float* __restrict__ x, const float* __restrict__ Wr, const float* __restrict__ br,
    float* __restrict__ acc_out)
{
    const int b = blockIdx.x;
    const int tid = threadIdx.x;
    const int d = tid & 63;
    const int part = __builtin_amdgcn_readfirstlane(tid >> 6);
    const float* gi = x + (size_t)b * 8192;
    float p = 0.f;
    for (int ii = 0; ii < 2048; ++ii) {
        int i = part * 2048 + ii;
        p += gi[i] * Wr[i * 64 + d];          // Wr coalesced across lanes, gi uniform
    }
    __shared__ float rr[256];
    rr[part * 64 + d] = p;
    __syncthreads();
    if (tid < 64) {
        float v = rr[d] + rr[64 + d] + rr[128 + d] + rr[192 + d];
        acc_out[b * 64 + d] = 0.1f * (v + br[d]);
    }
}

// ---------------------------------------------------------------------------
// K3: fused per-(expert, sequence) transformer forward.
// One 256-thread block per routed pair. lane r = sequence position (0..63),
// wg = wave id (0..3). Residual stream kept transposed bf16 in LDS: hsT[k][r].
// Weight reads are wave-uniform -> s_load broadcasts. Accumulators fp32 regs.
__global__ __launch_bounds__(256) void expert_kernel(
    const float* __restrict__ x,   const float* __restrict__ Win, const float* __restrict__ bin_,
    const float* __restrict__ Wq,  const float* __restrict__ bq,
    const float* __restrict__ Wk,  const float* __restrict__ bk,
    const float* __restrict__ Wv,  const float* __restrict__ bv,
    const float* __restrict__ Wo,  const float* __restrict__ bo,
    const float* __restrict__ ln1g, const float* __restrict__ ln1b,
    const float* __restrict__ ln2g, const float* __restrict__ ln2b,
    const float* __restrict__ W1,  const float* __restrict__ b1,
    const float* __restrict__ W2,  const float* __restrict__ b2,
    const float* __restrict__ Wout, const float* __restrict__ bout,
    const int* __restrict__ cnt, const int* __restrict__ rlist, const float* __restrict__ wlist,
    float* __restrict__ acc_out)
{
    const int e = blockIdx.x >> 9;
    const int s = blockIdx.x & 511;
    if (s >= cnt[e]) return;                  // uniform early-exit (over-launched grid)
    const int b   = rlist[e * 512 + s];
    const float wgt = wlist[e * 512 + s];
    const int tid = threadIdx.x;
    const int r   = tid & 63;
    const int wg  = __builtin_amdgcn_readfirstlane(tid >> 6);

    // LDS: 32KB residual (transposed bf16) + 31KB phase-overlaid region = 63KB
    __shared__ unsigned short hsT[256 * 64];                  // [k][r]
    __shared__ __align__(16) unsigned char regB[31744];
    unsigned short* xT  = (unsigned short*)regB;              // [128][64] bf16 (16KB)
    unsigned short* qT  = (unsigned short*)regB;              // [32][64]  (4KB)
    unsigned short* kT  = (unsigned short*)(regB + 4096);     // [32][64]
    unsigned short* vT  = (unsigned short*)(regB + 8192);     // [32][64]
    float*          ssT = (float*)(regB + 12288);             // [64][64] f32 (16KB)
    float*          avT = (float*)(regB + 12288);             // [32][64] f32 (aliases ssT)
    unsigned short* tT  = (unsigned short*)regB;              // [128][64] bf16 (16KB)
    float*          red = (float*)(regB + 28672);             // up to [64][4][2] f32 (2KB)
    float*          pooled = (float*)(regB + 30720);          // [256] f32 (1KB)

    // ---- P0: stage x[b] -> xT (bf16, transposed) ----
    {
        const float* xb = x + (size_t)b * 8192;
        #pragma unroll
        for (int i = 0; i < 32; ++i) {
            int id = tid + 256 * i;
            xT[(id & 127) * 64 + (id >> 7)] = f2b(xb[id]);
        }
    }
    __syncthreads();

    // ---- P1: h0 = x @ Win[e] + bin[e]  -> hsT ----
    {
        const float* Wp = Win + (size_t)e * (128 * 256);
        const float* bp = bin_ + e * 256;
        #pragma unroll
        for (int cb = 0; cb < 4; ++cb) {
            const int c0 = cb * 64 + wg * 16;
            float a16[16];
            #pragma unroll
            for (int j = 0; j < 16; ++j) a16[j] = bp[c0 + j];
            #pragma unroll 4
            for (int kk = 0; kk < 128; ++kk) {
                float a = b2f(xT[kk * 64 + r]);
                const float* wrow = Wp + kk * 256 + c0;
                #pragma unroll
                for (int j = 0; j < 16; ++j) a16[j] += a * wrow[j];
            }
            #pragma unroll
            for (int j = 0; j < 16; ++j) hsT[(c0 + j) * 64 + r] = f2b(a16[j]);
        }
    }
    __syncthreads();

    // LayerNorm over a 64-reg (row r, 64-col strip) accumulator; writes hsT.
    auto LNW = [&](float* a, const float* g, const float* bb) {
        float s1 = 0.f, s2 = 0.f;
        #pragma unroll
        for (int q = 0; q < 64; ++q) { s1 += a[q]; s2 += a[q] * a[q]; }
        red[(r * 4 + wg) * 2 + 0] = s1;
        red[(r * 4 + wg) * 2 + 1] = s2;
        __syncthreads();
        float S1 = red[r * 8 + 0] + red[r * 8 + 2] + red[r * 8 + 4] + red[r * 8 + 6];
        float S2 = red[r * 8 + 1] + red[r * 8 + 3] + red[r * 8 + 5] + red[r * 8 + 7];
        float m   = S1 * (1.f / 256.f);
        float var = S2 * (1.f / 256.f) - m * m;
        float rstd = rsqrtf(var + 1e-5f);
        #pragma unroll
        for (int cb = 0; cb < 4; ++cb)
            #pragma unroll
            for (int j = 0; j < 16; ++j) {
                int c = cb * 64 + wg * 16 + j;
                float v = (a[cb * 16 + j] - m) * rstd * g[c] + bb[c];
                a[cb * 16 + j] = v;
                hsT[c * 64 + r] = f2b(v);
            }
        __syncthreads();
    };

    // ---- transformer layers ----
    for (int l = 0; l < 2; ++l) {
        const int el = e * 2 + l;
        const float* Wq_p = Wq + (size_t)el * 65536; const float* bq_p = bq + el * 256;
        const float* Wk_p = Wk + (size_t)el * 65536; const float* bk_p = bk + el * 256;
        const float* Wv_p = Wv + (size_t)el * 65536; const float* bv_p = bv + el * 256;
        const float* Wo_p = Wo + (size_t)el * 65536; const float* bo_p = bo + el * 256;

        // o-proj accumulator: h + bo (attn output added per head)
        float oacc[64];
        #pragma unroll
        for (int cb = 0; cb < 4; ++cb)
            #pragma unroll
            for (int j = 0; j < 16; ++j) {
                int c = cb * 64 + wg * 16 + j;
                oacc[cb * 16 + j] = b2f(hsT[c * 64 + r]) + bo_p[c];
            }

        for (int h8 = 0; h8 < 8; ++h8) {
            // --- A: q,k,v head slices (each wave: 8 cols) ---
            {
                const int c0 = h8 * 32 + wg * 8;
                float qa[8], ka[8], va[8];
                #pragma unroll
                for (int jj = 0; jj < 8; ++jj) { qa[jj] = bq_p[c0 + jj]; ka[jj] = bk_p[c0 + jj]; va[jj] = bv_p[c0 + jj]; }
                #pragma unroll 4
                for (int kk = 0; kk < 256; ++kk) {
                    float a = b2f(hsT[kk * 64 + r]);
                    const float* wq = Wq_p + kk * 256 + c0;
                    const float* wk = Wk_p + kk * 256 + c0;
                    const float* wv = Wv_p + kk * 256 + c0;
                    #pragma unroll
                    for (int jj = 0; jj < 8; ++jj) {
                        qa[jj] += a * wq[jj];
                        ka[jj] += a * wk[jj];
                        va[jj] += a * wv[jj];
                    }
                }
                #pragma unroll
                for (int jj = 0; jj < 8; ++jj) {
                    qT[(wg * 8 + jj) * 64 + r] = f2b(qa[jj]);
                    kT[(wg * 8 + jj) * 64 + r] = f2b(ka[jj]);
                    vT[(wg * 8 + jj) * 64 + r] = f2b(va[jj]);
                }
            }
            __syncthreads();

            // --- B: scores row r, cols wg*16..+16; softmax across 4 waves ---
            float sc[16];
            {
                #pragma unroll
                for (int j = 0; j < 16; ++j) sc[j] = 0.f;
                #pragma unroll 4
                for (int d = 0; d < 32; ++d) {
                    float aq = b2f(qT[d * 64 + r]);
                    #pragma unroll
                    for (int j = 0; j < 16; ++j)
                        sc[j] += aq * b2f(kT[d * 64 + wg * 16 + j]);
                }
                const float sscale = 0.17677669529663687f;  // 1/sqrt(32)
                float mx = -1e30f;
                #pragma unroll
                for (int j = 0; j < 16; ++j) { sc[j] *= sscale; mx = fmaxf(mx, sc[j]); }
                red[r * 4 + wg] = mx;
                __syncthreads();
                mx = fmaxf(fmaxf(red[r * 4 + 0], red[r * 4 + 1]),
                           fmaxf(red[r * 4 + 2], red[r * 4 + 3]));
                float se = 0.f;
                #pragma unroll
                for (int j = 0; j < 16; ++j) { float ee = __expf(sc[j] - mx); sc[j] = ee; se += ee; }
                __syncthreads();
                red[r * 4 + wg] = se;
                __syncthreads();
                se = red[r * 4 + 0] + red[r * 4 + 1] + red[r * 4 + 2] + red[r * 4 + 3];
                float inv = 1.f / se;
                #pragma unroll
                for (int j = 0; j < 16; ++j) ssT[(wg * 16 + j) * 64 + r] = sc[j] * inv;
            }
            __syncthreads();

            // --- av = probs @ v  (row r, 8 head-dims per wave) ---
            float av8[8];
            #pragma unroll
            for (int jj = 0; jj < 8; ++jj) av8[jj] = 0.f;
            #pragma unroll 2
            for (int c = 0; c < 64; ++c) {
                float sv = ssT[c * 64 + r];
                #pragma unroll
                for (int jj = 0; jj < 8; ++jj)
                    av8[jj] += sv * b2f(vT[(wg * 8 + jj) * 64 + c]);
            }
            __syncthreads();                  // all ssT reads done (avT aliases it)
            #pragma unroll
            for (int jj = 0; jj < 8; ++jj) avT[(wg * 8 + jj) * 64 + r] = av8[jj];
            __syncthreads();

            // --- C: oacc += av_h @ Wo[h-rows] ---
            #pragma unroll
            for (int cb = 0; cb < 4; ++cb) {
                const int c0 = cb * 64 + wg * 16;
                #pragma unroll 4
                for (int kk = 0; kk < 32; ++kk) {
                    float a = avT[kk * 64 + r];
                    const float* wrow = Wo_p + (h8 * 32 + kk) * 256 + c0;
                    #pragma unroll
                    for (int j = 0; j < 16; ++j) oacc[cb * 16 + j] += a * wrow[j];
                }
            }
            __syncthreads();                  // avT dead before next head reuses region
        }

        // --- LN1 (h = LN(h + attn_out)) -> hsT ---
        LNW(oacc, ln1g + el * 256, ln1b + el * 256);

        // --- FF: facc = h + b2 + relu(h@W1+b1)@W2, tiled over 8 x 128 FF cols ---
        float facc[64];
        const float* b2_p = b2 + el * 256;
        #pragma unroll
        for (int cb = 0; cb < 4; ++cb)
            #pragma unroll
            for (int j = 0; j < 16; ++j)
                facc[cb * 16 + j] = oacc[cb * 16 + j] + b2_p[cb * 64 + wg * 16 + j];

        const float* W1_p = W1 + (size_t)el * (256 * 1024); const float* b1_p = b1 + el * 1024;
        const float* W2_p = W2 + (size_t)el * (1024 * 256);
        for (int T = 0; T < 8; ++T) {
            // E1: t = relu(h @ W1 tile + b1); each wave 32 FF cols
            float t1[32];
            const int f0 = T * 128 + wg * 32;
            #pragma unroll
            for (int j = 0; j < 32; ++j) t1[j] = b1_p[f0 + j];
            #pragma unroll 2
            for (int kk = 0; kk < 256; ++kk) {
                float a = b2f(hsT[kk * 64 + r]);
                const float* wrow = W1_p + kk * 1024 + f0;
                #pragma unroll
                for (int j = 0; j < 32; ++j) t1[j] += a * wrow[j];
            }
            #pragma unroll
            for (int j = 0; j < 32; ++j) tT[(wg * 32 + j) * 64 + r] = f2b(fmaxf(t1[j], 0.f));
            __syncthreads();
            // E2: facc += t @ W2 tile
            #pragma unroll
            for (int cb = 0; cb < 4; ++cb) {
                const int c0 = cb * 64 + wg * 16;
                #pragma unroll 2
                for (int kk = 0; kk < 128; ++kk) {
                    float a = b2f(tT[kk * 64 + r]);
                    const float* wrow = W2_p + (T * 128 + kk) * 256 + c0;
                    #pragma unroll
                    for (int j = 0; j < 16; ++j) facc[cb * 16 + j] += a * wrow[j];
                }
            }
            __syncthreads();                  // tT dead before next tile
        }

        // --- LN2 -> hsT ---
        LNW(facc, ln2g + el * 256, ln2b + el * 256);
    }

    // ---- pooling: pooled[c] = mean_r h[r][c] ----
    {
        int c = tid;
        float sum = 0.f;
        #pragma unroll
        for (int rr2 = 0; rr2 < 64; ++rr2) sum += b2f(hsT[c * 64 + rr2]);
        pooled[c] = sum * (1.f / 64.f);
    }
    __syncthreads();

    // ---- out_e = pooled @ Wout[e] + bout[e]; weighted atomic combine ----
    if (tid < 64) {
        const float* Wout_p = Wout + (size_t)e * (256 * 64);
        float o = bout[e * 64 + tid];
        for (int c = 0; c < 256; ++c) o += pooled[c] * Wout_p[c * 64 + tid];
        atomicAdd(&acc_out[b * 64 + tid], wgt * o);
    }
}

// ---------------------------------------------------------------------------
// K4: output layernorm over DO=64
__global__ __launch_bounds__(64) void final_ln_kernel(
    const float* __restrict__ acc_out, const float* __restrict__ on_g,
    const float* __restrict__ on_b, float* __restrict__ out)
{
    const int b = blockIdx.x;
    const int d = threadIdx.x;                // 0..63
    float v = acc_out[b * 64 + d];
    float s1 = v, s2 = v * v;
    #pragma unroll
    for (int st = 1; st < 64; st <<= 1) {
        s1 += __shfl_xor(s1, st, 64);
        s2 += __shfl_xor(s2, st, 64);
    }
    float m   = s1 * (1.f / 64.f);
    float var = s2 * (1.f / 64.f) - m * m;
    float rstd = rsqrtf(var + 1e-5f);
    out[b * 64 + d] = (v - m) * rstd * on_g[d] + on_b[d];
}

// ---------------------------------------------------------------------------
extern "C" void kernel_launch(void* const* d_in, const int* in_sizes, int n_in,
                              void* d_out, int out_size, void* d_ws, size_t ws_size,
                              hipStream_t stream)
{
    (void)in_sizes; (void)n_in; (void)out_size; (void)ws_size;
    const float* x    = (const float*)d_in[0];
    const float* Win  = (const float*)d_in[1];
    const float* bin_ = (const float*)d_in[2];
    const float* Wq   = (const float*)d_in[3];
    const float* bq   = (const float*)d_in[4];
    const float* Wk   = (const float*)d_in[5];
    const float* bk   = (const float*)d_in[6];
    const float* Wv   = (const float*)d_in[7];
    const float* bv   = (const float*)d_in[8];
    const float* Wo   = (const float*)d_in[9];
    const float* bo   = (const float*)d_in[10];
    const float* ln1g = (const float*)d_in[11];
    const float* ln1b = (const float*)d_in[12];
    const float* ln2g = (const float*)d_in[13];
    const float* ln2b = (const float*)d_in[14];
    const float* W1   = (const float*)d_in[15];
    const float* b1   = (const float*)d_in[16];
    const float* W2   = (const float*)d_in[17];
    const float* b2   = (const float*)d_in[18];
    const float* Wout = (const float*)d_in[19];
    const float* bout = (const float*)d_in[20];
    const float* Wg   = (const float*)d_in[21];
    const float* bg   = (const float*)d_in[22];
    const float* Wr   = (const float*)d_in[23];
    const float* br   = (const float*)d_in[24];
    const float* on_g = (const float*)d_in[25];
    const float* on_b = (const float*)d_in[26];
    float* out = (float*)d_out;

    // workspace carve-up (~164KB)
    char* ws = (char*)d_ws;
    float* acc_out = (float*)ws;                       // 512*64 f32 = 131072B
    int*   cnt     = (int*)(ws + 131072);              // 8 ints
    int*   rlist   = (int*)(ws + 131072 + 128);        // 8*512 ints
    float* wlist   = (float*)(ws + 131072 + 128 + 16384);

    zero_cnt_kernel<<<1, 64, 0, stream>>>(cnt);
    gate_kernel<<<512, 256, 0, stream>>>(x, Wg, bg, cnt, rlist, wlist);
    resproj_kernel<<<512, 256, 0, stream>>>(x, Wr, br, acc_out);
    expert_kernel<<<4096, 256, 0, stream>>>(x, Win, bin_, Wq, bq, Wk, bk, Wv, bv, Wo, bo,
        ln1g, ln1b, ln2g, ln2b, W1, b1, W2, b2, Wout, bout, cnt, rlist, wlist, acc_out);
    final_ln_kernel<<<512, 64, 0, stream>>>(acc_out, on_g, on_b, out);
}

// Round 2
// 2491.856 us; speedup vs baseline: 3.6828x; 3.6828x over previous
//
#include <hip/hip_runtime.h>
#include <hip/hip_bf16.h>

// B=512, S=64, IN=128, DM=256, H=8, HD=32, L=2, FF=1024, DO=64, E=8, K=2, GI=8192

typedef __attribute__((ext_vector_type(8))) short bf16x8;
typedef __attribute__((ext_vector_type(4))) float f32x4;
typedef __attribute__((ext_vector_type(4))) unsigned short u16x4;

#define DEVINL __device__ __forceinline__
#define MFMA16(a, b, c) __builtin_amdgcn_mfma_f32_16x16x32_bf16((a), (b), (c), 0, 0, 0)

DEVINL float b2f(unsigned short u) {
    unsigned int i = ((unsigned int)u) << 16;
    float f; __builtin_memcpy(&f, &i, 4); return f;
}
DEVINL unsigned short f2b(float f) {
    unsigned int i; __builtin_memcpy(&i, &f, 4);
    unsigned int r = (i + 0x7FFFu + ((i >> 16) & 1u)) >> 16;  // RTN-even
    return (unsigned short)r;
}

// ---------------------------------------------------------------------------
// K0: zero routing counters
__global__ void zero_cnt_kernel(int* __restrict__ cnt) {
    if (threadIdx.x < 8) cnt[threadIdx.x] = 0;
}

// ---------------------------------------------------------------------------
// convT: src fp32 [batch][R][C] -> dst bf16 [batch][C][R]  (B-operand layout)
__global__ __launch_bounds__(256) void convT_kernel(
    const float* __restrict__ src, short* __restrict__ dst, int R, int C, int total)
{
    int idx = blockIdx.x * 256 + threadIdx.x;
    if (idx >= total) return;
    int rc = R * C;
    int bM = idx / rc;
    int rem = idx - bM * rc;
    int c = rem / R;
    int r = rem - c * R;
    dst[idx] = (short)f2b(src[(size_t)bM * rc + (size_t)r * C + c]);
}

// ---------------------------------------------------------------------------
// K1: gate — double-precision logits (stable top-2 vs numpy ref)
__global__ __launch_bounds__(256) void gate_kernel(
    const float* __restrict__ x, const float* __restrict__ Wg, const float* __restrict__ bg,
    int* __restrict__ cnt, int* __restrict__ rlist, float* __restrict__ wlist)
{
    const int b = blockIdx.x;
    const int tid = threadIdx.x;
    const int e8 = tid & 7;
    const int seg = tid >> 3;
    const float* gi = x + (size_t)b * 8192;
    double p = 0.0;
    for (int ii = 0; ii < 256; ++ii) {
        int i = seg * 256 + ii;
        p += (double)gi[i] * (double)Wg[i * 8 + e8];
    }
    p += __shfl_xor(p, 8, 64);
    p += __shfl_xor(p, 16, 64);
    p += __shfl_xor(p, 32, 64);
    __shared__ double wred[4 * 8];
    const int lane = tid & 63, w = tid >> 6;
    if (lane < 8) wred[w * 8 + lane] = p;
    __syncthreads();
    if (tid == 0) {
        double lg[8];
        for (int e = 0; e < 8; ++e)
            lg[e] = wred[e] + wred[8 + e] + wred[16 + e] + wred[24 + e] + (double)bg[e];
        int i1 = 0;
        for (int e = 1; e < 8; ++e) if (lg[e] > lg[i1]) i1 = e;
        int i2 = (i1 == 0) ? 1 : 0;
        for (int e = 0; e < 8; ++e) if (e != i1 && lg[e] > lg[i2]) i2 = e;
        double ex = exp(lg[i2] - lg[i1]);
        float w1 = (float)(1.0 / (1.0 + ex));
        float w2 = (float)(ex / (1.0 + ex));
        int p1 = atomicAdd(&cnt[i1], 1);
        rlist[i1 * 512 + p1] = b; wlist[i1 * 512 + p1] = w1;
        int p2 = atomicAdd(&cnt[i2], 1);
        rlist[i2 * 512 + p2] = b; wlist[i2 * 512 + p2] = w2;
    }
}

// ---------------------------------------------------------------------------
// K2: residual projection — acc_out[b,d] = 0.1*(gi . Wr[:,d] + br[d])
__global__ __launch_bounds__(256) void resproj_kernel(
    const float* __restrict__ x, const float* __restrict__ Wr, const float* __restrict__ br,
    float* __restrict__ acc_out)
{
    const int b = blockIdx.x;
    const int tid = threadIdx.x;
    const int d = tid & 63;
    const int part = __builtin_amdgcn_readfirstlane(tid >> 6);
    const float* gi = x + (size_t)b * 8192;
    float p = 0.f;
    for (int ii = 0; ii < 2048; ++ii) {
        int i = part * 2048 + ii;
        p += gi[i] * Wr[i * 64 + d];
    }
    __shared__ float rr[256];
    rr[part * 64 + d] = p;
    __syncthreads();
    if (tid < 64) {
        float v = rr[d] + rr[64 + d] + rr[128 + d] + rr[192 + d];
        acc_out[b * 64 + d] = 0.1f * (v + br[d]);
    }
}

// ---------------------------------------------------------------------------
// K3: fused per-(expert, sequence) transformer — MFMA 16x16x32 bf16.
// Wave w owns rows 16w..16w+15 of the 64-row sequence for every GEMM.
// A-operands: bf16 row-major LDS (ds_read_b128 frags). B-operands: bf16
// pre-transposed [n][k] in workspace, read as global dwordx4 frags (L2-hot:
// ~128 blocks share each expert's weights). Residual + LN fp32 in registers
// (MFMA C-layout: col=nt*16+(lane&15), row=(lane>>4)*4+i). LN per-row via
// 16-lane xor-shuffles (rows never cross waves) -> FF needs no barriers.
__global__ __launch_bounds__(256, 2) void expert_kernel(
    const float* __restrict__ x,
    const short* __restrict__ WinT, const float* __restrict__ bin_,
    const short* __restrict__ WqT,  const float* __restrict__ bq,
    const short* __restrict__ WkT,  const float* __restrict__ bk,
    const short* __restrict__ WvT,  const float* __restrict__ bv,
    const short* __restrict__ WoT,  const float* __restrict__ bo,
    const float* __restrict__ ln1g, const float* __restrict__ ln1b,
    const float* __restrict__ ln2g, const float* __restrict__ ln2b,
    const short* __restrict__ W1T,  const float* __restrict__ b1,
    const short* __restrict__ W2T,  const float* __restrict__ b2,
    const float* __restrict__ Wout, const float* __restrict__ bout,
    const int* __restrict__ cnt, const int* __restrict__ rlist,
    const float* __restrict__ wlist, float* __restrict__ acc_out)
{
    const int e = blockIdx.x >> 9;
    const int s = blockIdx.x & 511;
    if (s >= cnt[e]) return;
    const int b   = rlist[e * 512 + s];
    const float wgt = wlist[e * 512 + s];
    const int tid = threadIdx.x;
    const int lane = tid & 63;
    const int wg  = __builtin_amdgcn_readfirstlane(tid >> 6);
    const int ln = lane & 15, quad = lane >> 4;
    const int mb = wg * 16;
    const int mrow = mb + ln;          // A-fragment row
    const int orow = mb + quad * 4;    // C-layout row base (+i)

    // LDS: h[64][264] + t[64][136](x-stage alias) + Q/O[64][40] + K[64][40]
    //      + VT[32][72] + P[64][72](pool-red alias) = 75,264 B -> 2 blocks/CU
    __shared__ __align__(16) unsigned char smem[75264];
    unsigned short* hS  = (unsigned short*)(smem);           // [64][264]
    unsigned short* tS  = (unsigned short*)(smem + 33792);   // [64][136]
    unsigned short* QS  = (unsigned short*)(smem + 51200);   // [64][40] (O alias)
    unsigned short* KS  = (unsigned short*)(smem + 56320);   // [64][40]
    unsigned short* VTS = (unsigned short*)(smem + 61440);   // [32][72]
    unsigned short* PS  = (unsigned short*)(smem + 66048);   // [64][72]
    float* redf = (float*)(smem + 66048);                    // [4][256] alias PS

    // ---- stage x[b] -> tS (bf16 row-major, A for Win GEMM) ----
    {
        const float* xb = x + (size_t)b * 8192;
        #pragma unroll
        for (int i = 0; i < 32; ++i) {
            int id = tid + 256 * i;
            tS[(id >> 7) * 136 + (id & 127)] = f2b(xb[id]);
        }
    }
    __syncthreads();

    f32x4 hr[16];   // residual stream, fp32, C-layout

    // ---- h0 = x @ Win[e] + bin[e] ----
    {
        const short* Wp = WinT + (size_t)e * 32768;   // [256][128]
        const float* bp = bin_ + e * 256;
        bf16x8 af[4];
        #pragma unroll
        for (int kt = 0; kt < 4; ++kt)
            af[kt] = *(const bf16x8*)&tS[mrow * 136 + kt * 32 + quad * 8];
        #pragma unroll
        for (int nt = 0; nt < 16; ++nt) {
            int col = nt * 16 + ln;
            float bz = bp[col];
            f32x4 c = {bz, bz, bz, bz};
            const short* wp = Wp + col * 128 + quad * 8;
            #pragma unroll
            for (int kt = 0; kt < 4; ++kt)
                c = MFMA16(af[kt], *(const bf16x8*)(wp + kt * 32), c);
            hr[nt] = c;
            #pragma unroll
            for (int i = 0; i < 4; ++i) hS[(orow + i) * 264 + col] = f2b(c[i]);
        }
    }
    // no barrier: hS rows mb..mb+15 written & read only by this wave

    for (int l = 0; l < 2; ++l) {
        const int el = e * 2 + l;
        const short* WqT_p = WqT + (size_t)el * 65536;
        const short* WkT_p = WkT + (size_t)el * 65536;
        const short* WvT_p = WvT + (size_t)el * 65536;
        const short* WoT_p = WoT + (size_t)el * 65536;
        const float* bq_p = bq + el * 256;
        const float* bk_p = bk + el * 256;
        const float* bv_p = bv + el * 256;
        const float* bo_p = bo + el * 256;

        // oacc = h + bo; heads accumulate av@Wo into it
        f32x4 oacc[16];
        #pragma unroll
        for (int nt = 0; nt < 16; ++nt) {
            float bz = bo_p[nt * 16 + ln];
            f32x4 t = hr[nt];
            t[0] += bz; t[1] += bz; t[2] += bz; t[3] += bz;
            oacc[nt] = t;
        }

        for (int h8 = 0; h8 < 8; ++h8) {
            bf16x8 af[8];
            #pragma unroll
            for (int kt = 0; kt < 8; ++kt)
                af[kt] = *(const bf16x8*)&hS[mrow * 264 + kt * 32 + quad * 8];
            // --- QKV head slice (N=32 each) ---
            #pragma unroll
            for (int m3 = 0; m3 < 3; ++m3) {
                const short* Wm = (m3 == 0) ? WqT_p : (m3 == 1) ? WkT_p : WvT_p;
                const float* bm = (m3 == 0) ? bq_p : (m3 == 1) ? bk_p : bv_p;
                #pragma unroll
                for (int nt2 = 0; nt2 < 2; ++nt2) {
                    int hc = nt2 * 16 + ln;
                    int col = h8 * 32 + hc;
                    float bz = bm[col];
                    f32x4 c = {bz, bz, bz, bz};
                    const short* wp = Wm + (size_t)col * 256 + quad * 8;
                    #pragma unroll
                    for (int kt = 0; kt < 8; ++kt)
                        c = MFMA16(af[kt], *(const bf16x8*)(wp + kt * 32), c);
                    if (m3 == 0) {
                        #pragma unroll
                        for (int i = 0; i < 4; ++i) QS[(orow + i) * 40 + hc] = f2b(c[i]);
                    } else if (m3 == 1) {
                        #pragma unroll
                        for (int i = 0; i < 4; ++i) KS[(orow + i) * 40 + hc] = f2b(c[i]);
                    } else {                      // V -> VT[hd][kpos], b64 write
                        u16x4 pk;
                        #pragma unroll
                        for (int i = 0; i < 4; ++i) pk[i] = f2b(c[i]);
                        *(u16x4*)&VTS[hc * 72 + orow] = pk;
                    }
                }
            }
            __syncthreads();   // K/VT cross-wave visible

            // --- scores = QK^T * scale; per-row softmax (16-lane groups) ---
            bf16x8 aq = *(const bf16x8*)&QS[mrow * 40 + quad * 8];
            f32x4 sc[4];
            #pragma unroll
            for (int nt4 = 0; nt4 < 4; ++nt4) {
                f32x4 z = {0.f, 0.f, 0.f, 0.f};
                sc[nt4] = MFMA16(aq, *(const bf16x8*)&KS[(nt4 * 16 + ln) * 40 + quad * 8], z);
            }
            const float sscale = 0.17677669529663687f;  // 1/sqrt(32)
            #pragma unroll
            for (int nt4 = 0; nt4 < 4; ++nt4)
                #pragma unroll
                for (int i = 0; i < 4; ++i) sc[nt4][i] *= sscale;
            #pragma unroll
            for (int i = 0; i < 4; ++i) {
                float m_ = fmaxf(fmaxf(sc[0][i], sc[1][i]), fmaxf(sc[2][i], sc[3][i]));
                m_ = fmaxf(m_, __shfl_xor(m_, 1));
                m_ = fmaxf(m_, __shfl_xor(m_, 2));
                m_ = fmaxf(m_, __shfl_xor(m_, 4));
                m_ = fmaxf(m_, __shfl_xor(m_, 8));
                float s_ = 0.f;
                #pragma unroll
                for (int nt4 = 0; nt4 < 4; ++nt4) {
                    sc[nt4][i] = __expf(sc[nt4][i] - m_); s_ += sc[nt4][i];
                }
                s_ += __shfl_xor(s_, 1); s_ += __shfl_xor(s_, 2);
                s_ += __shfl_xor(s_, 4); s_ += __shfl_xor(s_, 8);
                float inv = 1.f / s_;
                #pragma unroll
                for (int nt4 = 0; nt4 < 4; ++nt4)
                    PS[(orow + i) * 72 + nt4 * 16 + ln] = f2b(sc[nt4][i] * inv);
            }

            // --- av = P @ V (K=64, 2 steps) -> O (alias QS, own rows) ---
            bf16x8 ap0 = *(const bf16x8*)&PS[mrow * 72 + quad * 8];
            bf16x8 ap1 = *(const bf16x8*)&PS[mrow * 72 + 32 + quad * 8];
            #pragma unroll
            for (int nt2 = 0; nt2 < 2; ++nt2) {
                int hc = nt2 * 16 + ln;
                f32x4 c = {0.f, 0.f, 0.f, 0.f};
                c = MFMA16(ap0, *(const bf16x8*)&VTS[hc * 72 + quad * 8], c);
                c = MFMA16(ap1, *(const bf16x8*)&VTS[hc * 72 + 32 + quad * 8], c);
                #pragma unroll
                for (int i = 0; i < 4; ++i) QS[(orow + i) * 40 + hc] = f2b(c[i]);
            }
            __syncthreads();   // all waves done reading KS/VTS before next head

            // --- oacc += O_h @ Wo[h8*32.., :] (K=32, 1 step) ---
            bf16x8 ao = *(const bf16x8*)&QS[mrow * 40 + quad * 8];
            #pragma unroll
            for (int nt = 0; nt < 16; ++nt) {
                const short* wp = WoT_p + (size_t)(nt * 16 + ln) * 256 + h8 * 32 + quad * 8;
                oacc[nt] = MFMA16(ao, *(const bf16x8*)wp, oacc[nt]);
            }
        }

        // --- LN1 (in-wave, per row) -> hr, hS ---
        {
            const float* g1 = ln1g + el * 256;
            const float* bb1 = ln1b + el * 256;
            float gv[16], bv2[16];
            #pragma unroll
            for (int nt = 0; nt < 16; ++nt) { gv[nt] = g1[nt * 16 + ln]; bv2[nt] = bb1[nt * 16 + ln]; }
            #pragma unroll
            for (int i = 0; i < 4; ++i) {
                float s1 = 0.f, s2 = 0.f;
                #pragma unroll
                for (int nt = 0; nt < 16; ++nt) { float v = oacc[nt][i]; s1 += v; s2 += v * v; }
                s1 += __shfl_xor(s1, 1); s1 += __shfl_xor(s1, 2);
                s1 += __shfl_xor(s1, 4); s1 += __shfl_xor(s1, 8);
                s2 += __shfl_xor(s2, 1); s2 += __shfl_xor(s2, 2);
                s2 += __shfl_xor(s2, 4); s2 += __shfl_xor(s2, 8);
                float m_ = s1 * (1.f / 256.f);
                float rstd = rsqrtf(s2 * (1.f / 256.f) - m_ * m_ + 1e-5f);
                #pragma unroll
                for (int nt = 0; nt < 16; ++nt) {
                    float v = (oacc[nt][i] - m_) * rstd * gv[nt] + bv2[nt];
                    hr[nt][i] = v;
                    hS[(orow + i) * 264 + nt * 16 + ln] = f2b(v);
                }
            }
        }

        // --- FF (no barriers: t rows are wave-private) ---
        {
            const float* b2_p = b2 + el * 256;
            f32x4 facc[16];
            #pragma unroll
            for (int nt = 0; nt < 16; ++nt) {
                float bz = b2_p[nt * 16 + ln];
                f32x4 t = hr[nt];
                t[0] += bz; t[1] += bz; t[2] += bz; t[3] += bz;
                facc[nt] = t;
            }
            bf16x8 ah[8];
            #pragma unroll
            for (int kt = 0; kt < 8; ++kt)
                ah[kt] = *(const bf16x8*)&hS[mrow * 264 + kt * 32 + quad * 8];
            const short* W1T_p = W1T + (size_t)el * 262144;   // [1024][256]
            const short* W2T_p = W2T + (size_t)el * 262144;   // [256][1024]
            const float* b1_p = b1 + el * 1024;
            for (int ch = 0; ch < 8; ++ch) {
                f32x4 tacc[8];
                #pragma unroll
                for (int nf = 0; nf < 8; ++nf) {
                    int col1 = ch * 128 + nf * 16 + ln;
                    float bz = b1_p[col1];
                    f32x4 c = {bz, bz, bz, bz};
                    const short* wp = W1T_p + (size_t)col1 * 256 + quad * 8;
                    #pragma unroll
                    for (int kt = 0; kt < 8; ++kt)
                        c = MFMA16(ah[kt], *(const bf16x8*)(wp + kt * 32), c);
                    tacc[nf] = c;
                }
                #pragma unroll
                for (int nf = 0; nf < 8; ++nf)
                    #pragma unroll
                    for (int i = 0; i < 4; ++i)
                        tS[(orow + i) * 136 + nf * 16 + ln] = f2b(fmaxf(tacc[nf][i], 0.f));
                bf16x8 at[4];
                #pragma unroll
                for (int kt = 0; kt < 4; ++kt)
                    at[kt] = *(const bf16x8*)&tS[mrow * 136 + kt * 32 + quad * 8];
                #pragma unroll
                for (int nt = 0; nt < 16; ++nt) {
                    const short* wp = W2T_p + (size_t)(nt * 16 + ln) * 1024 + ch * 128 + quad * 8;
                    #pragma unroll
                    for (int kt = 0; kt < 4; ++kt)
                        facc[nt] = MFMA16(at[kt], *(const bf16x8*)(wp + kt * 32), facc[nt]);
                }
            }

            // --- LN2 -> hr, hS ---
            const float* g2 = ln2g + el * 256;
            const float* bb2 = ln2b + el * 256;
            float gv[16], bv2[16];
            #pragma unroll
            for (int nt = 0; nt < 16; ++nt) { gv[nt] = g2[nt * 16 + ln]; bv2[nt] = bb2[nt * 16 + ln]; }
            #pragma unroll
            for (int i = 0; i < 4; ++i) {
                float s1 = 0.f, s2 = 0.f;
                #pragma unroll
                for (int nt = 0; nt < 16; ++nt) { float v = facc[nt][i]; s1 += v; s2 += v * v; }
                s1 += __shfl_xor(s1, 1); s1 += __shfl_xor(s1, 2);
                s1 += __shfl_xor(s1, 4); s1 += __shfl_xor(s1, 8);
                s2 += __shfl_xor(s2, 1); s2 += __shfl_xor(s2, 2);
                s2 += __shfl_xor(s2, 4); s2 += __shfl_xor(s2, 8);
                float m_ = s1 * (1.f / 256.f);
                float rstd = rsqrtf(s2 * (1.f / 256.f) - m_ * m_ + 1e-5f);
                #pragma unroll
                for (int nt = 0; nt < 16; ++nt) {
                    float v = (facc[nt][i] - m_) * rstd * gv[nt] + bv2[nt];
                    hr[nt][i] = v;
                    hS[(orow + i) * 264 + nt * 16 + ln] = f2b(v);
                }
            }
        }
    }

    // ---- pooling (register reduction) + Wout + weighted combine ----
    {
        float cs[16];
        #pragma unroll
        for (int nt = 0; nt < 16; ++nt) {
            cs[nt] = hr[nt][0] + hr[nt][1] + hr[nt][2] + hr[nt][3];
            cs[nt] += __shfl_xor(cs[nt], 16);
            cs[nt] += __shfl_xor(cs[nt], 32);
        }
        if (lane < 16) {
            #pragma unroll
            for (int nt = 0; nt < 16; ++nt) redf[wg * 256 + nt * 16 + lane] = cs[nt];
        }
        __syncthreads();
        if (tid < 64) {
            const float* Wout_p = Wout + (size_t)e * (256 * 64);
            float o = bout[e * 64 + tid];
            for (int c = 0; c < 256; ++c) {
                float pv = (redf[c] + redf[256 + c] + redf[512 + c] + redf[768 + c]) * (1.f / 64.f);
                o += pv * Wout_p[c * 64 + tid];
            }
            atomicAdd(&acc_out[b * 64 + tid], wgt * o);
        }
    }
}

// ---------------------------------------------------------------------------
// K4: output layernorm over DO=64
__global__ __launch_bounds__(64) void final_ln_kernel(
    const float* __restrict__ acc_out, const float* __restrict__ on_g,
    const float* __restrict__ on_b, float* __restrict__ out)
{
    const int b = blockIdx.x;
    const int d = threadIdx.x;
    float v = acc_out[b * 64 + d];
    float s1 = v, s2 = v * v;
    #pragma unroll
    for (int st = 1; st < 64; st <<= 1) {
        s1 += __shfl_xor(s1, st, 64);
        s2 += __shfl_xor(s2, st, 64);
    }
    float m   = s1 * (1.f / 64.f);
    float var = s2 * (1.f / 64.f) - m * m;
    float rstd = rsqrtf(var + 1e-5f);
    out[b * 64 + d] = (v - m) * rstd * on_g[d] + on_b[d];
}

// ---------------------------------------------------------------------------
extern "C" void kernel_launch(void* const* d_in, const int* in_sizes, int n_in,
                              void* d_out, int out_size, void* d_ws, size_t ws_size,
                              hipStream_t stream)
{
    (void)in_sizes; (void)n_in; (void)out_size; (void)ws_size;
    const float* x    = (const float*)d_in[0];
    const float* Win  = (const float*)d_in[1];
    const float* bin_ = (const float*)d_in[2];
    const float* Wq   = (const float*)d_in[3];
    const float* bq   = (const float*)d_in[4];
    const float* Wk   = (const float*)d_in[5];
    const float* bk   = (const float*)d_in[6];
    const float* Wv   = (const float*)d_in[7];
    const float* bv   = (const float*)d_in[8];
    const float* Wo   = (const float*)d_in[9];
    const float* bo   = (const float*)d_in[10];
    const float* ln1g = (const float*)d_in[11];
    const float* ln1b = (const float*)d_in[12];
    const float* ln2g = (const float*)d_in[13];
    const float* ln2b = (const float*)d_in[14];
    const float* W1   = (const float*)d_in[15];
    const float* b1   = (const float*)d_in[16];
    const float* W2   = (const float*)d_in[17];
    const float* b2   = (const float*)d_in[18];
    const float* Wout = (const float*)d_in[19];
    const float* bout = (const float*)d_in[20];
    const float* Wg   = (const float*)d_in[21];
    const float* bg   = (const float*)d_in[22];
    const float* Wr   = (const float*)d_in[23];
    const float* br   = (const float*)d_in[24];
    const float* on_g = (const float*)d_in[25];
    const float* on_b = (const float*)d_in[26];
    float* out = (float*)d_out;

    // workspace carve-up
    char* ws = (char*)d_ws;
    float* acc_out = (float*)ws;                         // 131072 B
    int*   cnt     = (int*)(ws + 131072);                // 32 B (pad to 128)
    int*   rlist   = (int*)(ws + 131200);                // 16384 B
    float* wlist   = (float*)(ws + 147584);              // 16384 B
    short* WinT    = (short*)(ws + 164096);              //   524,288 B
    short* WqT     = (short*)(ws + 688384);              // 2,097,152 B
    short* WkT     = (short*)(ws + 2785536);
    short* WvT     = (short*)(ws + 4882688);
    short* WoT     = (short*)(ws + 6979840);
    short* W1T     = (short*)(ws + 9076992);             // 8,388,608 B
    short* W2T     = (short*)(ws + 17465600);            // 8,388,608 B
    // total: 25,854,208 B

    // weight transposition fp32 [R][C] -> bf16 [C][R]
    convT_kernel<<<(262144 + 255) / 256, 256, 0, stream>>>(Win, WinT, 128, 256, 262144);
    convT_kernel<<<(1048576 + 255) / 256, 256, 0, stream>>>(Wq, WqT, 256, 256, 1048576);
    convT_kernel<<<(1048576 + 255) / 256, 256, 0, stream>>>(Wk, WkT, 256, 256, 1048576);
    convT_kernel<<<(1048576 + 255) / 256, 256, 0, stream>>>(Wv, WvT, 256, 256, 1048576);
    convT_kernel<<<(1048576 + 255) / 256, 256, 0, stream>>>(Wo, WoT, 256, 256, 1048576);
    convT_kernel<<<(4194304 + 255) / 256, 256, 0, stream>>>(W1, W1T, 256, 1024, 4194304);
    convT_kernel<<<(4194304 + 255) / 256, 256, 0, stream>>>(W2, W2T, 1024, 256, 4194304);

    zero_cnt_kernel<<<1, 64, 0, stream>>>(cnt);
    gate_kernel<<<512, 256, 0, stream>>>(x, Wg, bg, cnt, rlist, wlist);
    resproj_kernel<<<512, 256, 0, stream>>>(x, Wr, br, acc_out);
    expert_kernel<<<4096, 256, 0, stream>>>(x,
        WinT, bin_, WqT, bq, WkT, bk, WvT, bv, WoT, bo,
        ln1g, ln1b, ln2g, ln2b, W1T, b1, W2T, b2, Wout, bout,
        cnt, rlist, wlist, acc_out);
    final_ln_kernel<<<512, 64, 0, stream>>>(acc_out, on_g, on_b, out);
}

// Round 3
// 1318.044 us; speedup vs baseline: 6.9626x; 1.8906x over previous
//
#include <hip/hip_runtime.h>
#include <hip/hip_bf16.h>

// B=512, S=64, IN=128, DM=256, H=8, HD=32, L=2, FF=1024, DO=64, E=8, K=2, GI=8192

typedef __attribute__((ext_vector_type(8))) short bf16x8;
typedef __attribute__((ext_vector_type(4))) float f32x4;
typedef __attribute__((ext_vector_type(4))) unsigned short u16x4;

#define DEVINL __device__ __forceinline__
#define MFMA16(a, b, c) __builtin_amdgcn_mfma_f32_16x16x32_bf16((a), (b), (c), 0, 0, 0)

DEVINL float b2f(unsigned short u) {
    unsigned int i = ((unsigned int)u) << 16;
    float f; __builtin_memcpy(&f, &i, 4); return f;
}
DEVINL unsigned short f2b(float f) {
    unsigned int i; __builtin_memcpy(&i, &f, 4);
    unsigned int r = (i + 0x7FFFu + ((i >> 16) & 1u)) >> 16;  // RTN-even
    return (unsigned short)r;
}

// async global->LDS, 16B per lane; lds dest = wave-uniform base + lane*16
DEVINL void g2l16(const short* g, short* l) {
    __builtin_amdgcn_global_load_lds(
        (const __attribute__((address_space(1))) unsigned int*)g,
        (__attribute__((address_space(3))) unsigned int*)l, 16, 0, 0);
}

// ---------------------------------------------------------------------------
__global__ void zero_cnt_kernel(int* __restrict__ cnt) {
    if (threadIdx.x < 8) cnt[threadIdx.x] = 0;
}

// ---------------------------------------------------------------------------
// Weight-image builders: fp32 [K][N] -> bf16 chunked images.
// Chunk = 4096 shorts = [CC cols][K k] with k-group (8 shorts) XOR-swizzled by
// (col&7) (or col&3 for K=32) so stage-buffer ds_read_b128 is bank-balanced.
__global__ __launch_bounds__(256) void conv_cols_kernel(
    const float* __restrict__ src, short* __restrict__ dst,
    int K, int N, int CC, int total)
{
    int idx = blockIdx.x * 256 + threadIdx.x;
    if (idx >= total) return;
    int KN = K * N;
    int mat = idx / KN;
    int r = idx - mat * KN;
    int CK = CC * K;
    int c = r / CK;
    int r2 = r - c * CK;
    int j = r2 / K;
    int kslot = r2 - j * K;
    int ksrc = ((((kslot >> 3) ^ (j & 7)) << 3) | (kslot & 7));
    dst[idx] = (short)f2b(src[(size_t)mat * KN + (size_t)ksrc * N + c * CC + j]);
}

// Wo image: per el, chunk (h8*2+hf) = [128 cols (hf half)][32 k of head h8]
__global__ __launch_bounds__(256) void conv_oproj_kernel(
    const float* __restrict__ src, short* __restrict__ dst, int total)
{
    int idx = blockIdx.x * 256 + threadIdx.x;
    if (idx >= total) return;
    int el = idx >> 16;
    int r = idx & 65535;
    int cc = r >> 12;
    int r2 = r & 4095;
    int j = r2 >> 5;
    int kslot = r2 & 31;
    int ksrc = ((((kslot >> 3) ^ (j & 3)) << 3) | (kslot & 7));
    int h8 = cc >> 1, hf = cc & 1;
    dst[idx] = (short)f2b(src[(size_t)el * 65536 + (size_t)(h8 * 32 + ksrc) * 256 + hf * 128 + j]);
}

// W2 image: per el, chunk (ch*8+i) = [32 cols at 32i][128 k of slice ch]
__global__ __launch_bounds__(256) void conv_w2_kernel(
    const float* __restrict__ src, short* __restrict__ dst, int total)
{
    int idx = blockIdx.x * 256 + threadIdx.x;
    if (idx >= total) return;
    int el = idx >> 18;
    int r = idx & 262143;
    int cc = r >> 12;
    int r2 = r & 4095;
    int j = r2 >> 7;
    int kslot = r2 & 127;
    int ksrc = ((((kslot >> 3) ^ (j & 7)) << 3) | (kslot & 7));
    int ch = cc >> 3, i = cc & 7;
    dst[idx] = (short)f2b(src[(size_t)el * 262144 + (size_t)(ch * 128 + ksrc) * 256 + i * 32 + j]);
}

// ---------------------------------------------------------------------------
// gate: double-precision logits (stable top-2 vs numpy ref)
__global__ __launch_bounds__(256) void gate_kernel(
    const float* __restrict__ x, const float* __restrict__ Wg, const float* __restrict__ bg,
    int* __restrict__ cnt, int* __restrict__ rlist, float* __restrict__ wlist)
{
    const int b = blockIdx.x;
    const int tid = threadIdx.x;
    const int e8 = tid & 7;
    const int seg = tid >> 3;
    const float* gi = x + (size_t)b * 8192;
    double p = 0.0;
    for (int ii = 0; ii < 256; ++ii) {
        int i = seg * 256 + ii;
        p += (double)gi[i] * (double)Wg[i * 8 + e8];
    }
    p += __shfl_xor(p, 8, 64);
    p += __shfl_xor(p, 16, 64);
    p += __shfl_xor(p, 32, 64);
    __shared__ double wred[4 * 8];
    const int lane = tid & 63, w = tid >> 6;
    if (lane < 8) wred[w * 8 + lane] = p;
    __syncthreads();
    if (tid == 0) {
        double lg[8];
        for (int e = 0; e < 8; ++e)
            lg[e] = wred[e] + wred[8 + e] + wred[16 + e] + wred[24 + e] + (double)bg[e];
        int i1 = 0;
        for (int e = 1; e < 8; ++e) if (lg[e] > lg[i1]) i1 = e;
        int i2 = (i1 == 0) ? 1 : 0;
        for (int e = 0; e < 8; ++e) if (e != i1 && lg[e] > lg[i2]) i2 = e;
        double ex = exp(lg[i2] - lg[i1]);
        float w1 = (float)(1.0 / (1.0 + ex));
        float w2 = (float)(ex / (1.0 + ex));
        int p1 = atomicAdd(&cnt[i1], 1);
        rlist[i1 * 512 + p1] = b; wlist[i1 * 512 + p1] = w1;
        int p2 = atomicAdd(&cnt[i2], 1);
        rlist[i2 * 512 + p2] = b; wlist[i2 * 512 + p2] = w2;
    }
}

// ---------------------------------------------------------------------------
// resproj: 8 batch rows per block -> Wr stream reused 8x (1GB -> 128MB L2)
__global__ __launch_bounds__(256) void resproj_kernel(
    const float* __restrict__ x, const float* __restrict__ Wr, const float* __restrict__ br,
    float* __restrict__ acc_out)
{
    const int b0 = blockIdx.x * 8;
    const int tid = threadIdx.x;
    const int d = tid & 63;
    const int part = tid >> 6;
    float acc[8];
    #pragma unroll
    for (int k = 0; k < 8; ++k) acc[k] = 0.f;
    for (int ii = 0; ii < 2048; ++ii) {
        int i = part * 2048 + ii;
        float wv = Wr[i * 64 + d];
        #pragma unroll
        for (int k = 0; k < 8; ++k) acc[k] += x[(size_t)(b0 + k) * 8192 + i] * wv;
    }
    __shared__ float rr[4][8][64];
    #pragma unroll
    for (int k = 0; k < 8; ++k) rr[part][k][d] = acc[k];
    __syncthreads();
    if (tid < 64) {
        #pragma unroll
        for (int k = 0; k < 8; ++k) {
            float v = rr[0][k][tid] + rr[1][k][tid] + rr[2][k][tid] + rr[3][k][tid];
            acc_out[(b0 + k) * 64 + tid] = 0.1f * (v + br[tid]);
        }
    }
}

// ---------------------------------------------------------------------------
// expert kernel — MFMA + LDS-staged weights (392-chunk ring, double buffer)
// + XCD pinning: expert = blockIdx&7 (blockIdx%8 -> XCD) so each XCD's L2
// holds exactly one expert's 3.2MB weight image.
#define STEP(nextp) do { __syncthreads(); const short* _np = (nextp); if (_np) { \
        short* _d = &STG[slot ^ 1][0]; \
        g2l16(_np + tid * 8, _d + (tid & 192) * 8); \
        g2l16(_np + 2048 + tid * 8, _d + 2048 + (tid & 192) * 8); } } while (0)

__global__ __launch_bounds__(256, 2) void expert_kernel(
    const float* __restrict__ x,
    const short* __restrict__ WinI, const float* __restrict__ bin_,
    const short* __restrict__ WqI,  const float* __restrict__ bq,
    const short* __restrict__ WkI,  const float* __restrict__ bk,
    const short* __restrict__ WvI,  const float* __restrict__ bv,
    const short* __restrict__ WoI,  const float* __restrict__ bo,
    const float* __restrict__ ln1g, const float* __restrict__ ln1b,
    const float* __restrict__ ln2g, const float* __restrict__ ln2b,
    const short* __restrict__ W1I,  const float* __restrict__ b1,
    const short* __restrict__ W2I,  const float* __restrict__ b2,
    const float* __restrict__ Wout, const float* __restrict__ bout,
    const int* __restrict__ cnt, const int* __restrict__ rlist,
    const float* __restrict__ wlist, float* __restrict__ acc_out)
{
    const int e = blockIdx.x & 7;          // XCD pin
    const int s = blockIdx.x >> 3;
    if (s >= cnt[e]) return;
    const int b   = rlist[e * 512 + s];
    const float wgt = wlist[e * 512 + s];
    const int tid = threadIdx.x;
    const int lane = tid & 63;
    const int wg  = __builtin_amdgcn_readfirstlane(tid >> 6);
    const int ln = lane & 15, quad = lane >> 4;
    const int mb = wg * 16;
    const int mrow = mb + ln;
    const int orow = mb + quad * 4;

    __shared__ unsigned short hS[64 * 264];                 // 33792 B residual (bf16 row-major)
    __shared__ __align__(16) short STG[2][4096];            // 16384 B weight ring buffer
    __shared__ __align__(16) unsigned char attnB[24064];    // attn bufs / tS / redf overlay
    unsigned short* tS  = (unsigned short*)attnB;           // [64][136]
    unsigned short* QS  = (unsigned short*)attnB;           // [64][40]
    unsigned short* KS  = (unsigned short*)(attnB + 5120);  // [64][40]
    unsigned short* VTS = (unsigned short*)(attnB + 10240); // [32][72]
    unsigned short* PS  = (unsigned short*)(attnB + 14848); // [64][72]
    float* redf = (float*)(attnB + 14848);                  // [4][256]

    int slot = 0;
    const short* WinE = WinI + e * 32768;
    // prefetch chunk 0 (Win c0) before x-staging
    g2l16(WinE + tid * 8, &STG[0][(tid & 192) * 8]);
    g2l16(WinE + 2048 + tid * 8, &STG[0][2048 + (tid & 192) * 8]);

    // stage x[b] -> tS (bf16 row-major)
    {
        const float* xb = x + (size_t)b * 8192;
        #pragma unroll
        for (int i = 0; i < 32; ++i) {
            int id = tid + 256 * i;
            tS[(id >> 7) * 136 + (id & 127)] = f2b(xb[id]);
        }
    }
    __syncthreads();   // tS visible + chunk0 arrived (vmcnt drain)

    f32x4 hr[16];

    // ---- h0 = x @ Win[e] + bin[e] : 8 chunk-steps ----
    {
        bf16x8 afx[4];
        #pragma unroll
        for (int kt = 0; kt < 4; ++kt)
            afx[kt] = *(const bf16x8*)&tS[mrow * 136 + kt * 32 + quad * 8];
        const float* bp = bin_ + e * 256;
        const short* WqE0 = WqI + (size_t)(e * 2) * 65536;
        for (int c = 0; c < 8; ++c) {
            const short* nxt = (c < 7) ? (WinE + (c + 1) * 4096) : WqE0;
            STEP(nxt);
            const short* sg = &STG[slot][0];
            #pragma unroll
            for (int nt2 = 0; nt2 < 2; ++nt2) {
                const int nt = 2 * c + nt2;
                const int j = nt2 * 16 + ln;
                float bz = bp[nt * 16 + ln];
                f32x4 cc = {bz, bz, bz, bz};
                #pragma unroll
                for (int kt = 0; kt < 4; ++kt)
                    cc = MFMA16(afx[kt],
                        *(const bf16x8*)(sg + j * 128 + (((kt * 4 + quad) ^ (j & 7)) << 3)), cc);
                hr[nt] = cc;
                #pragma unroll
                for (int i = 0; i < 4; ++i) hS[(orow + i) * 264 + nt * 16 + ln] = f2b(cc[i]);
            }
            slot ^= 1;
        }
    }

    for (int l = 0; l < 2; ++l) {
        const int el = e * 2 + l;
        const short* WqE = WqI + (size_t)el * 65536;
        const short* WkE = WkI + (size_t)el * 65536;
        const short* WvE = WvI + (size_t)el * 65536;
        const short* WoE = WoI + (size_t)el * 65536;
        const short* W1E = W1I + (size_t)el * 262144;
        const short* W2E = W2I + (size_t)el * 262144;
        const float* bq_p = bq + el * 256;
        const float* bk_p = bk + el * 256;
        const float* bv_p = bv + el * 256;
        const float* bo_p = bo + el * 256;

        f32x4 oacc[16];
        #pragma unroll
        for (int nt = 0; nt < 16; ++nt) {
            float bz = bo_p[nt * 16 + ln];
            f32x4 t = hr[nt];
            t[0] += bz; t[1] += bz; t[2] += bz; t[3] += bz;
            oacc[nt] = t;
        }

        for (int h8 = 0; h8 < 8; ++h8) {
            bf16x8 af[8];
            #pragma unroll
            for (int kt = 0; kt < 8; ++kt)
                af[kt] = *(const bf16x8*)&hS[mrow * 264 + kt * 32 + quad * 8];

            // --- QKV: 6 chunk-steps (q0 q1 k0 k1 v0 v1) ---
            #pragma unroll
            for (int m3 = 0; m3 < 3; ++m3) {
                const short* cur = (m3 == 0 ? WqE : m3 == 1 ? WkE : WvE) + h8 * 8192;
                const float* bm = (m3 == 0 ? bq_p : m3 == 1 ? bk_p : bv_p);
                #pragma unroll
                for (int hf = 0; hf < 2; ++hf) {
                    const short* nxt = (hf == 0) ? (cur + 4096)
                                      : (m3 == 0 ? WkE + h8 * 8192
                                       : m3 == 1 ? WvE + h8 * 8192
                                                 : WoE + h8 * 8192);
                    STEP(nxt);
                    const short* sg = &STG[slot][0];
                    const int hc = hf * 16 + ln;
                    float bz = bm[h8 * 32 + hc];
                    f32x4 c0 = {bz, bz, bz, bz};
                    f32x4 c1 = {0.f, 0.f, 0.f, 0.f};
                    #pragma unroll
                    for (int kt = 0; kt < 8; kt += 2) {
                        c0 = MFMA16(af[kt],
                            *(const bf16x8*)(sg + ln * 256 + (((kt * 4 + quad) ^ (ln & 7)) << 3)), c0);
                        c1 = MFMA16(af[kt + 1],
                            *(const bf16x8*)(sg + ln * 256 + ((((kt + 1) * 4 + quad) ^ (ln & 7)) << 3)), c1);
                    }
                    c0 = c0 + c1;
                    if (m3 == 0) {
                        #pragma unroll
                        for (int i = 0; i < 4; ++i) QS[(orow + i) * 40 + hc] = f2b(c0[i]);
                    } else if (m3 == 1) {
                        #pragma unroll
                        for (int i = 0; i < 4; ++i) KS[(orow + i) * 40 + hc] = f2b(c0[i]);
                    } else {
                        u16x4 pk;
                        #pragma unroll
                        for (int i = 0; i < 4; ++i) pk[i] = f2b(c0[i]);
                        *(u16x4*)&VTS[hc * 72 + orow] = pk;
                    }
                    slot ^= 1;
                }
            }
            __syncthreads();   // K/VT cross-wave visible (Wo chunk0 in flight)

            // --- scores + in-wave softmax (rows wave-private) ---
            bf16x8 aq = *(const bf16x8*)&QS[mrow * 40 + quad * 8];
            f32x4 sc[4];
            #pragma unroll
            for (int nt4 = 0; nt4 < 4; ++nt4) {
                f32x4 z = {0.f, 0.f, 0.f, 0.f};
                sc[nt4] = MFMA16(aq, *(const bf16x8*)&KS[(nt4 * 16 + ln) * 40 + quad * 8], z);
            }
            const float sscale = 0.17677669529663687f;  // 1/sqrt(32)
            #pragma unroll
            for (int nt4 = 0; nt4 < 4; ++nt4)
                #pragma unroll
                for (int i = 0; i < 4; ++i) sc[nt4][i] *= sscale;
            #pragma unroll
            for (int i = 0; i < 4; ++i) {
                float m_ = fmaxf(fmaxf(sc[0][i], sc[1][i]), fmaxf(sc[2][i], sc[3][i]));
                m_ = fmaxf(m_, __shfl_xor(m_, 1));
                m_ = fmaxf(m_, __shfl_xor(m_, 2));
                m_ = fmaxf(m_, __shfl_xor(m_, 4));
                m_ = fmaxf(m_, __shfl_xor(m_, 8));
                float s_ = 0.f;
                #pragma unroll
                for (int nt4 = 0; nt4 < 4; ++nt4) {
                    sc[nt4][i] = __expf(sc[nt4][i] - m_); s_ += sc[nt4][i];
                }
                s_ += __shfl_xor(s_, 1); s_ += __shfl_xor(s_, 2);
                s_ += __shfl_xor(s_, 4); s_ += __shfl_xor(s_, 8);
                float inv = 1.f / s_;
                #pragma unroll
                for (int nt4 = 0; nt4 < 4; ++nt4)
                    PS[(orow + i) * 72 + nt4 * 16 + ln] = f2b(sc[nt4][i] * inv);
            }

            // --- av = P @ V -> QS (own rows) ---
            bf16x8 ap0 = *(const bf16x8*)&PS[mrow * 72 + quad * 8];
            bf16x8 ap1 = *(const bf16x8*)&PS[mrow * 72 + 32 + quad * 8];
            #pragma unroll
            for (int nt2 = 0; nt2 < 2; ++nt2) {
                const int hc = nt2 * 16 + ln;
                f32x4 c = {0.f, 0.f, 0.f, 0.f};
                c = MFMA16(ap0, *(const bf16x8*)&VTS[hc * 72 + quad * 8], c);
                c = MFMA16(ap1, *(const bf16x8*)&VTS[hc * 72 + 32 + quad * 8], c);
                #pragma unroll
                for (int i = 0; i < 4; ++i) QS[(orow + i) * 40 + hc] = f2b(c[i]);
            }

            // --- O-proj: 2 chunk-steps ---
            bf16x8 ao = *(const bf16x8*)&QS[mrow * 40 + quad * 8];
            #pragma unroll
            for (int hf = 0; hf < 2; ++hf) {
                const short* nxt = (hf == 0) ? (WoE + h8 * 8192 + 4096)
                                  : (h8 < 7 ? WqE + (h8 + 1) * 8192 : W1E);
                STEP(nxt);
                const short* sg = &STG[slot][0];
                #pragma unroll
                for (int nt8 = 0; nt8 < 8; ++nt8) {
                    const int j = nt8 * 16 + ln;
                    oacc[hf * 8 + nt8] = MFMA16(ao,
                        *(const bf16x8*)(sg + j * 32 + ((quad ^ (j & 3)) << 3)), oacc[hf * 8 + nt8]);
                }
                slot ^= 1;
            }
        }

        // --- LN1 (in-wave) -> hr, hS ---
        {
            const float* g1 = ln1g + el * 256;
            const float* bb1 = ln1b + el * 256;
            float gv[16], bv2[16];
            #pragma unroll
            for (int nt = 0; nt < 16; ++nt) { gv[nt] = g1[nt * 16 + ln]; bv2[nt] = bb1[nt * 16 + ln]; }
            #pragma unroll
            for (int i = 0; i < 4; ++i) {
                float s1 = 0.f, s2 = 0.f;
                #pragma unroll
                for (int nt = 0; nt < 16; ++nt) { float v = oacc[nt][i]; s1 += v; s2 += v * v; }
                s1 += __shfl_xor(s1, 1); s1 += __shfl_xor(s1, 2);
                s1 += __shfl_xor(s1, 4); s1 += __shfl_xor(s1, 8);
                s2 += __shfl_xor(s2, 1); s2 += __shfl_xor(s2, 2);
                s2 += __shfl_xor(s2, 4); s2 += __shfl_xor(s2, 8);
                float m_ = s1 * (1.f / 256.f);
                float rstd = rsqrtf(s2 * (1.f / 256.f) - m_ * m_ + 1e-5f);
                #pragma unroll
                for (int nt = 0; nt < 16; ++nt) {
                    float v = (oacc[nt][i] - m_) * rstd * gv[nt] + bv2[nt];
                    hr[nt][i] = v;
                    hS[(orow + i) * 264 + nt * 16 + ln] = f2b(v);
                }
            }
        }

        // --- FF: 8 ch x (8 W1-steps + 8 W2-steps) ---
        {
            const float* b2_p = b2 + el * 256;
            f32x4 facc[16];
            #pragma unroll
            for (int nt = 0; nt < 16; ++nt) {
                float bz = b2_p[nt * 16 + ln];
                f32x4 t = hr[nt];
                t[0] += bz; t[1] += bz; t[2] += bz; t[3] += bz;
                facc[nt] = t;
            }
            bf16x8 ah[8];
            #pragma unroll
            for (int kt = 0; kt < 8; ++kt)
                ah[kt] = *(const bf16x8*)&hS[mrow * 264 + kt * 32 + quad * 8];
            const float* b1_p = b1 + el * 1024;
            for (int ch = 0; ch < 8; ++ch) {
                for (int i = 0; i < 8; ++i) {
                    const short* nxt = (i < 7) ? (W1E + ch * 32768 + (i + 1) * 4096)
                                               : (W2E + ch * 32768);
                    STEP(nxt);
                    const short* sg = &STG[slot][0];
                    float bz = b1_p[ch * 128 + i * 16 + ln];
                    f32x4 c0 = {bz, bz, bz, bz};
                    f32x4 c1 = {0.f, 0.f, 0.f, 0.f};
                    #pragma unroll
                    for (int kt = 0; kt < 8; kt += 2) {
                        c0 = MFMA16(ah[kt],
                            *(const bf16x8*)(sg + ln * 256 + (((kt * 4 + quad) ^ (ln & 7)) << 3)), c0);
                        c1 = MFMA16(ah[kt + 1],
                            *(const bf16x8*)(sg + ln * 256 + ((((kt + 1) * 4 + quad) ^ (ln & 7)) << 3)), c1);
                    }
                    c0 = c0 + c1;
                    #pragma unroll
                    for (int ii = 0; ii < 4; ++ii)
                        tS[(orow + ii) * 136 + i * 16 + ln] = f2b(fmaxf(c0[ii], 0.f));
                    slot ^= 1;
                }
                bf16x8 at4[4];
                #pragma unroll
                for (int kt = 0; kt < 4; ++kt)
                    at4[kt] = *(const bf16x8*)&tS[mrow * 136 + kt * 32 + quad * 8];
                for (int i = 0; i < 8; ++i) {
                    const short* nxt = (i < 7) ? (W2E + ch * 32768 + (i + 1) * 4096)
                                      : (ch < 7 ? W1E + (ch + 1) * 32768
                                       : (l == 0 ? WqI + (size_t)(el + 1) * 65536
                                                 : (const short*)nullptr));
                    STEP(nxt);
                    const short* sg = &STG[slot][0];
                    #pragma unroll
                    for (int nt2 = 0; nt2 < 2; ++nt2) {
                        const int j = nt2 * 16 + ln;
                        const int nt = 2 * i + nt2;
                        f32x4 cc = facc[nt];
                        #pragma unroll
                        for (int kt = 0; kt < 4; ++kt)
                            cc = MFMA16(at4[kt],
                                *(const bf16x8*)(sg + j * 128 + (((kt * 4 + quad) ^ (j & 7)) << 3)), cc);
                        facc[nt] = cc;
                    }
                    slot ^= 1;
                }
            }

            // --- LN2 (in-wave) -> hr, hS ---
            const float* g2 = ln2g + el * 256;
            const float* bb2 = ln2b + el * 256;
            float gv[16], bv2[16];
            #pragma unroll
            for (int nt = 0; nt < 16; ++nt) { gv[nt] = g2[nt * 16 + ln]; bv2[nt] = bb2[nt * 16 + ln]; }
            #pragma unroll
            for (int i = 0; i < 4; ++i) {
                float s1 = 0.f, s2 = 0.f;
                #pragma unroll
                for (int nt = 0; nt < 16; ++nt) { float v = facc[nt][i]; s1 += v; s2 += v * v; }
                s1 += __shfl_xor(s1, 1); s1 += __shfl_xor(s1, 2);
                s1 += __shfl_xor(s1, 4); s1 += __shfl_xor(s1, 8);
                s2 += __shfl_xor(s2, 1); s2 += __shfl_xor(s2, 2);
                s2 += __shfl_xor(s2, 4); s2 += __shfl_xor(s2, 8);
                float m_ = s1 * (1.f / 256.f);
                float rstd = rsqrtf(s2 * (1.f / 256.f) - m_ * m_ + 1e-5f);
                #pragma unroll
                for (int nt = 0; nt < 16; ++nt) {
                    float v = (facc[nt][i] - m_) * rstd * gv[nt] + bv2[nt];
                    hr[nt][i] = v;
                    hS[(orow + i) * 264 + nt * 16 + ln] = f2b(v);
                }
            }
        }
    }

    // ---- pooling + Wout + weighted combine ----
    {
        float cs[16];
        #pragma unroll
        for (int nt = 0; nt < 16; ++nt) {
            cs[nt] = hr[nt][0] + hr[nt][1] + hr[nt][2] + hr[nt][3];
            cs[nt] += __shfl_xor(cs[nt], 16);
            cs[nt] += __shfl_xor(cs[nt], 32);
        }
        __syncthreads();   // all waves done with tS/PS region before redf reuse
        if (lane < 16) {
            #pragma unroll
            for (int nt = 0; nt < 16; ++nt) redf[wg * 256 + nt * 16 + lane] = cs[nt];
        }
        __syncthreads();
        if (tid < 64) {
            const float* Wout_p = Wout + (size_t)e * (256 * 64);
            float o = bout[e * 64 + tid];
            for (int c = 0; c < 256; ++c) {
                float pv = (redf[c] + redf[256 + c] + redf[512 + c] + redf[768 + c]) * (1.f / 64.f);
                o += pv * Wout_p[c * 64 + tid];
            }
            atomicAdd(&acc_out[b * 64 + tid], wgt * o);
        }
    }
}

// ---------------------------------------------------------------------------
__global__ __launch_bounds__(64) void final_ln_kernel(
    const float* __restrict__ acc_out, const float* __restrict__ on_g,
    const float* __restrict__ on_b, float* __restrict__ out)
{
    const int b = blockIdx.x;
    const int d = threadIdx.x;
    float v = acc_out[b * 64 + d];
    float s1 = v, s2 = v * v;
    #pragma unroll
    for (int st = 1; st < 64; st <<= 1) {
        s1 += __shfl_xor(s1, st, 64);
        s2 += __shfl_xor(s2, st, 64);
    }
    float m   = s1 * (1.f / 64.f);
    float var = s2 * (1.f / 64.f) - m * m;
    float rstd = rsqrtf(var + 1e-5f);
    out[b * 64 + d] = (v - m) * rstd * on_g[d] + on_b[d];
}

// ---------------------------------------------------------------------------
extern "C" void kernel_launch(void* const* d_in, const int* in_sizes, int n_in,
                              void* d_out, int out_size, void* d_ws, size_t ws_size,
                              hipStream_t stream)
{
    (void)in_sizes; (void)n_in; (void)out_size; (void)ws_size;
    const float* x    = (const float*)d_in[0];
    const float* Win  = (const float*)d_in[1];
    const float* bin_ = (const float*)d_in[2];
    const float* Wq   = (const float*)d_in[3];
    const float* bq   = (const float*)d_in[4];
    const float* Wk   = (const float*)d_in[5];
    const float* bk   = (const float*)d_in[6];
    const float* Wv   = (const float*)d_in[7];
    const float* bv   = (const float*)d_in[8];
    const float* Wo   = (const float*)d_in[9];
    const float* bo   = (const float*)d_in[10];
    const float* ln1g = (const float*)d_in[11];
    const float* ln1b = (const float*)d_in[12];
    const float* ln2g = (const float*)d_in[13];
    const float* ln2b = (const float*)d_in[14];
    const float* W1   = (const float*)d_in[15];
    const float* b1   = (const float*)d_in[16];
    const float* W2   = (const float*)d_in[17];
    const float* b2   = (const float*)d_in[18];
    const float* Wout = (const float*)d_in[19];
    const float* bout = (const float*)d_in[20];
    const float* Wg   = (const float*)d_in[21];
    const float* bg   = (const float*)d_in[22];
    const float* Wr   = (const float*)d_in[23];
    const float* br   = (const float*)d_in[24];
    const float* on_g = (const float*)d_in[25];
    const float* on_b = (const float*)d_in[26];
    float* out = (float*)d_out;

    // workspace carve-up
    char* ws = (char*)d_ws;
    float* acc_out = (float*)ws;                         // 131072 B
    int*   cnt     = (int*)(ws + 131072);
    int*   rlist   = (int*)(ws + 131200);                // 16384 B
    float* wlist   = (float*)(ws + 147584);              // 16384 B
    short* WinT    = (short*)(ws + 164096);              //   524,288 B
    short* WqT     = (short*)(ws + 688384);              // 2,097,152 B
    short* WkT     = (short*)(ws + 2785536);
    short* WvT     = (short*)(ws + 4882688);
    short* WoT     = (short*)(ws + 6979840);
    short* W1T     = (short*)(ws + 9076992);             // 8,388,608 B
    short* W2T     = (short*)(ws + 17465600);            // 8,388,608 B

    conv_cols_kernel<<<1024, 256, 0, stream>>>(Win, WinT, 128, 256, 32, 262144);
    conv_cols_kernel<<<4096, 256, 0, stream>>>(Wq, WqT, 256, 256, 16, 1048576);
    conv_cols_kernel<<<4096, 256, 0, stream>>>(Wk, WkT, 256, 256, 16, 1048576);
    conv_cols_kernel<<<4096, 256, 0, stream>>>(Wv, WvT, 256, 256, 16, 1048576);
    conv_oproj_kernel<<<4096, 256, 0, stream>>>(Wo, WoT, 1048576);
    conv_cols_kernel<<<16384, 256, 0, stream>>>(W1, W1T, 256, 1024, 16, 4194304);
    conv_w2_kernel<<<16384, 256, 0, stream>>>(W2, W2T, 4194304);

    zero_cnt_kernel<<<1, 64, 0, stream>>>(cnt);
    gate_kernel<<<512, 256, 0, stream>>>(x, Wg, bg, cnt, rlist, wlist);
    resproj_kernel<<<64, 256, 0, stream>>>(x, Wr, br, acc_out);
    expert_kernel<<<4096, 256, 0, stream>>>(x,
        WinT, bin_, WqT, bq, WkT, bk, WvT, bv, WoT, bo,
        ln1g, ln1b, ln2g, ln2b, W1T, b1, W2T, b2, Wout, bout,
        cnt, rlist, wlist, acc_out);
    final_ln_kernel<<<512, 64, 0, stream>>>(acc_out, on_g, on_b, out);
}

// Round 4
// 1237.444 us; speedup vs baseline: 7.4161x; 1.0651x over previous
//
#include <hip/hip_runtime.h>
#include <hip/hip_bf16.h>

// B=512, S=64, IN=128, DM=256, H=8, HD=32, L=2, FF=1024, DO=64, E=8, K=2, GI=8192

typedef __attribute__((ext_vector_type(8))) short bf16x8;
typedef __attribute__((ext_vector_type(4))) float f32x4;

#define DEVINL __device__ __forceinline__
#define MFMA16(a, b, c) __builtin_amdgcn_mfma_f32_16x16x32_bf16((a), (b), (c), 0, 0, 0)

DEVINL float b2f(unsigned short u) {
    unsigned int i = ((unsigned int)u) << 16;
    float f; __builtin_memcpy(&f, &i, 4); return f;
}
DEVINL unsigned short f2b(float f) {
    unsigned int i; __builtin_memcpy(&i, &f, 4);
    unsigned int r = (i + 0x7FFFu + ((i >> 16) & 1u)) >> 16;  // RTN-even
    return (unsigned short)r;
}

// ---------------------------------------------------------------------------
__global__ void zero_cnt_kernel(int* __restrict__ cnt) {
    if (threadIdx.x < 8) cnt[threadIdx.x] = 0;
}

// ---------------------------------------------------------------------------
// convT: src fp32 [batch][R][C] -> dst bf16 [batch][C][R]  (B-operand layout)
__global__ __launch_bounds__(256) void convT_kernel(
    const float* __restrict__ src, short* __restrict__ dst, int R, int C, int total)
{
    int idx = blockIdx.x * 256 + threadIdx.x;
    if (idx >= total) return;
    int rc = R * C;
    int bM = idx / rc;
    int rem = idx - bM * rc;
    int c = rem / R;
    int r = rem - c * R;
    dst[idx] = (short)f2b(src[(size_t)bM * rc + (size_t)r * C + c]);
}

// ---------------------------------------------------------------------------
// gate: double-precision logits (stable top-2 vs numpy ref)
__global__ __launch_bounds__(256) void gate_kernel(
    const float* __restrict__ x, const float* __restrict__ Wg, const float* __restrict__ bg,
    int* __restrict__ cnt, int* __restrict__ rlist, float* __restrict__ wlist)
{
    const int b = blockIdx.x;
    const int tid = threadIdx.x;
    const int e8 = tid & 7;
    const int seg = tid >> 3;
    const float* gi = x + (size_t)b * 8192;
    double p = 0.0;
    for (int ii = 0; ii < 256; ++ii) {
        int i = seg * 256 + ii;
        p += (double)gi[i] * (double)Wg[i * 8 + e8];
    }
    p += __shfl_xor(p, 8, 64);
    p += __shfl_xor(p, 16, 64);
    p += __shfl_xor(p, 32, 64);
    __shared__ double wred[4 * 8];
    const int lane = tid & 63, w = tid >> 6;
    if (lane < 8) wred[w * 8 + lane] = p;
    __syncthreads();
    if (tid == 0) {
        double lg[8];
        for (int e = 0; e < 8; ++e)
            lg[e] = wred[e] + wred[8 + e] + wred[16 + e] + wred[24 + e] + (double)bg[e];
        int i1 = 0;
        for (int e = 1; e < 8; ++e) if (lg[e] > lg[i1]) i1 = e;
        int i2 = (i1 == 0) ? 1 : 0;
        for (int e = 0; e < 8; ++e) if (e != i1 && lg[e] > lg[i2]) i2 = e;
        double ex = exp(lg[i2] - lg[i1]);
        float w1 = (float)(1.0 / (1.0 + ex));
        float w2 = (float)(ex / (1.0 + ex));
        int p1 = atomicAdd(&cnt[i1], 1);
        rlist[i1 * 512 + p1] = b; wlist[i1 * 512 + p1] = w1;
        int p2 = atomicAdd(&cnt[i2], 1);
        rlist[i2 * 512 + p2] = b; wlist[i2 * 512 + p2] = w2;
    }
}

// ---------------------------------------------------------------------------
// resproj: 8 batch rows per block -> Wr stream reused 8x
__global__ __launch_bounds__(256) void resproj_kernel(
    const float* __restrict__ x, const float* __restrict__ Wr, const float* __restrict__ br,
    float* __restrict__ acc_out)
{
    const int b0 = blockIdx.x * 8;
    const int tid = threadIdx.x;
    const int d = tid & 63;
    const int part = tid >> 6;
    float acc[8];
    #pragma unroll
    for (int k = 0; k < 8; ++k) acc[k] = 0.f;
    for (int ii = 0; ii < 2048; ++ii) {
        int i = part * 2048 + ii;
        float wv = Wr[i * 64 + d];
        #pragma unroll
        for (int k = 0; k < 8; ++k) acc[k] += x[(size_t)(b0 + k) * 8192 + i] * wv;
    }
    __shared__ float rr[4][8][64];
    #pragma unroll
    for (int k = 0; k < 8; ++k) rr[part][k][d] = acc[k];
    __syncthreads();
    if (tid < 64) {
        #pragma unroll
        for (int k = 0; k < 8; ++k) {
            float v = rr[0][k][tid] + rr[1][k][tid] + rr[2][k][tid] + rr[3][k][tid];
            acc_out[(b0 + k) * 64 + tid] = 0.1f * (v + br[tid]);
        }
    }
}

// ---------------------------------------------------------------------------
// expert kernel — N-partitioned MFMA: wave wg owns output cols [wg*64,wg*64+64)
// of every GEMM. B-frags are wave-private global_load_dwordx4 (deep pipeline,
// no barriers inside a GEMM phase); A-frags come from shared LDS (hS).
// Attention: wave's cols = its 2 heads -> fully wave-private (no barriers).
// XCD pin: e = blockIdx&7 so each XCD's L2 holds one expert's 3.2MB image.
__global__ __launch_bounds__(256, 1) void expert_kernel(
    const float* __restrict__ x,
    const short* __restrict__ WinT, const float* __restrict__ bin_,
    const short* __restrict__ WqT,  const float* __restrict__ bq,
    const short* __restrict__ WkT,  const float* __restrict__ bk,
    const short* __restrict__ WvT,  const float* __restrict__ bv,
    const short* __restrict__ WoT,  const float* __restrict__ bo,
    const float* __restrict__ ln1g, const float* __restrict__ ln1b,
    const float* __restrict__ ln2g, const float* __restrict__ ln2b,
    const short* __restrict__ W1T,  const float* __restrict__ b1,
    const short* __restrict__ W2T,  const float* __restrict__ b2,
    const float* __restrict__ Wout, const float* __restrict__ bout,
    const int* __restrict__ cnt, const int* __restrict__ rlist,
    const float* __restrict__ wlist, float* __restrict__ acc_out)
{
    const int e = blockIdx.x & 7;          // XCD pin
    const int s = blockIdx.x >> 3;
    if (s >= cnt[e]) return;
    const int b   = rlist[e * 512 + s];
    const float wgt = wlist[e * 512 + s];
    const int tid = threadIdx.x;
    const int lane = tid & 63;
    const int wg  = __builtin_amdgcn_readfirstlane(tid >> 6);
    const int ln = lane & 15, quad = lane >> 4;
    const int nb = wg * 64;                // wave's output-column base

    // LDS: 33,792 + 55,296 + 2,048 + 1,024 = 92,160 B -> 1 block/CU
    __shared__ unsigned short hS[64 * 264];          // residual / av / LN out (A-source)
    __shared__ __align__(16) unsigned short attnS[4 * 6912];  // per-wave attn | xS | tS
    __shared__ float redS[512];                      // LN cross-wave partials
    __shared__ float pooledS[256];
    unsigned short* Qw  = attnS + wg * 6912;         // [64][36]
    unsigned short* Kw  = Qw + 2304;                 // [64][36]
    unsigned short* VTw = Qw + 4608;                 // [32][72]
    unsigned short* PSw = Qw;                        // [64][72] overlays Q+K
    unsigned short* xS  = attnS;                     // [64][136] (block-shared, P0/P1)
    unsigned short* tS  = attnS;                     // [64][136] (block-shared, FF)

    // ---- P0: stage x[b] -> xS bf16 row-major ----
    {
        const float* xb = x + (size_t)b * 8192;
        #pragma unroll
        for (int i = 0; i < 32; ++i) {
            int id = tid + 256 * i;
            xS[(id >> 7) * 136 + (id & 127)] = f2b(xb[id]);
        }
    }
    __syncthreads();

    f32x4 hr[16];   // residual, wave's 64 cols x 64 rows, C-layout [rt*4+ct]

    // ---- P1: h0 = x @ Win + bin (K=128) ----
    {
        const short* BW = WinT + (size_t)e * 32768;
        const float* bp = bin_ + e * 256;
        bf16x8 Bf[16];
        #pragma unroll
        for (int ct = 0; ct < 4; ++ct)
            #pragma unroll
            for (int kt = 0; kt < 4; ++kt)
                Bf[ct * 4 + kt] = *(const bf16x8*)(BW + (size_t)(nb + ct * 16 + ln) * 128 + kt * 32 + quad * 8);
        float bz[4];
        #pragma unroll
        for (int ct = 0; ct < 4; ++ct) bz[ct] = bp[nb + ct * 16 + ln];
        #pragma unroll
        for (int rt = 0; rt < 4; ++rt) {
            bf16x8 Af[4];
            #pragma unroll
            for (int kt = 0; kt < 4; ++kt)
                Af[kt] = *(const bf16x8*)&xS[(rt * 16 + ln) * 136 + kt * 32 + quad * 8];
            #pragma unroll
            for (int ct = 0; ct < 4; ++ct) {
                f32x4 c = {bz[ct], bz[ct], bz[ct], bz[ct]};
                #pragma unroll
                for (int kt = 0; kt < 4; ++kt) c = MFMA16(Af[kt], Bf[ct * 4 + kt], c);
                hr[rt * 4 + ct] = c;
                #pragma unroll
                for (int i = 0; i < 4; ++i)
                    hS[(rt * 16 + quad * 4 + i) * 264 + nb + ct * 16 + ln] = f2b(c[i]);
            }
        }
    }
    __syncthreads();

    // LayerNorm over acc (C-layout); cross-wave via redS; writes hr + hS.
    auto LN = [&](f32x4* a, const float* g, const float* bb) {
        #pragma unroll
        for (int rt = 0; rt < 4; ++rt)
            #pragma unroll
            for (int i = 0; i < 4; ++i) {
                float s1 = 0.f, s2 = 0.f;
                #pragma unroll
                for (int ct = 0; ct < 4; ++ct) { float v = a[rt * 4 + ct][i]; s1 += v; s2 += v * v; }
                s1 += __shfl_xor(s1, 1); s1 += __shfl_xor(s1, 2);
                s1 += __shfl_xor(s1, 4); s1 += __shfl_xor(s1, 8);
                s2 += __shfl_xor(s2, 1); s2 += __shfl_xor(s2, 2);
                s2 += __shfl_xor(s2, 4); s2 += __shfl_xor(s2, 8);
                if (ln == 0) {
                    int row = rt * 16 + quad * 4 + i;
                    redS[row * 8 + wg * 2] = s1;
                    redS[row * 8 + wg * 2 + 1] = s2;
                }
            }
        __syncthreads();
        float gv[4], bv2[4];
        #pragma unroll
        for (int ct = 0; ct < 4; ++ct) { gv[ct] = g[nb + ct * 16 + ln]; bv2[ct] = bb[nb + ct * 16 + ln]; }
        #pragma unroll
        for (int rt = 0; rt < 4; ++rt)
            #pragma unroll
            for (int i = 0; i < 4; ++i) {
                int row = rt * 16 + quad * 4 + i;
                float S1 = redS[row * 8 + 0] + redS[row * 8 + 2] + redS[row * 8 + 4] + redS[row * 8 + 6];
                float S2 = redS[row * 8 + 1] + redS[row * 8 + 3] + redS[row * 8 + 5] + redS[row * 8 + 7];
                float m_ = S1 * (1.f / 256.f);
                float rstd = rsqrtf(S2 * (1.f / 256.f) - m_ * m_ + 1e-5f);
                #pragma unroll
                for (int ct = 0; ct < 4; ++ct) {
                    float v = (a[rt * 4 + ct][i] - m_) * rstd * gv[ct] + bv2[ct];
                    hr[rt * 4 + ct][i] = v;
                    hS[row * 264 + nb + ct * 16 + ln] = f2b(v);
                }
            }
        __syncthreads();
    };

    for (int l = 0; l < 2; ++l) {
        const int el = e * 2 + l;
        const short* WqE = WqT + (size_t)el * 65536;
        const short* WkE = WkT + (size_t)el * 65536;
        const short* WvE = WvT + (size_t)el * 65536;
        const short* WoE = WoT + (size_t)el * 65536;
        const short* W1E = W1T + (size_t)el * 262144;
        const short* W2E = W2T + (size_t)el * 262144;
        const float* bq_p = bq + el * 256;
        const float* bk_p = bk + el * 256;
        const float* bv_p = bv + el * 256;
        const float* bo_p = bo + el * 256;

        f32x4 avr[16];   // both heads' av: [hp*8 + rt*2 + ct2]

        // ---- QKV + attention, wave-private, per head ----
        #pragma unroll
        for (int hp = 0; hp < 2; ++hp) {
            const int hb = nb + hp * 32;   // head (2wg+hp) col base

            auto qkv = [&](const short* WB, const float* bbp, unsigned short* dQK, int isV) {
                bf16x8 Bq[16];
                #pragma unroll
                for (int ct2 = 0; ct2 < 2; ++ct2)
                    #pragma unroll
                    for (int kt = 0; kt < 8; ++kt)
                        Bq[ct2 * 8 + kt] = *(const bf16x8*)(WB + (size_t)(hb + ct2 * 16 + ln) * 256 + kt * 32 + quad * 8);
                float bz2[2];
                #pragma unroll
                for (int ct2 = 0; ct2 < 2; ++ct2) bz2[ct2] = bbp[hb + ct2 * 16 + ln];
                #pragma unroll
                for (int rt = 0; rt < 4; ++rt) {
                    bf16x8 Af[8];
                    #pragma unroll
                    for (int kt = 0; kt < 8; ++kt)
                        Af[kt] = *(const bf16x8*)&hS[(rt * 16 + ln) * 264 + kt * 32 + quad * 8];
                    #pragma unroll
                    for (int ct2 = 0; ct2 < 2; ++ct2) {
                        f32x4 c = {bz2[ct2], bz2[ct2], bz2[ct2], bz2[ct2]};
                        #pragma unroll
                        for (int kt = 0; kt < 8; ++kt) c = MFMA16(Af[kt], Bq[ct2 * 8 + kt], c);
                        if (!isV) {
                            #pragma unroll
                            for (int i = 0; i < 4; ++i)
                                dQK[(rt * 16 + quad * 4 + i) * 36 + ct2 * 16 + ln] = f2b(c[i]);
                        } else {
                            #pragma unroll
                            for (int i = 0; i < 4; ++i)
                                VTw[(ct2 * 16 + ln) * 72 + rt * 16 + quad * 4 + i] = f2b(c[i]);
                        }
                    }
                }
            };
            qkv(WqE, bq_p, Qw, 0);
            qkv(WkE, bk_p, Kw, 0);
            qkv(WvE, bv_p, nullptr, 1);

            // --- S = Q K^T (M=64,N=64,K=32), wave-private ---
            f32x4 sc[16];
            {
                bf16x8 Bk[4];
                #pragma unroll
                for (int ck = 0; ck < 4; ++ck)
                    Bk[ck] = *(const bf16x8*)&Kw[(ck * 16 + ln) * 36 + quad * 8];
                #pragma unroll
                for (int rt = 0; rt < 4; ++rt) {
                    bf16x8 Aq = *(const bf16x8*)&Qw[(rt * 16 + ln) * 36 + quad * 8];
                    #pragma unroll
                    for (int ck = 0; ck < 4; ++ck) {
                        f32x4 z = {0.f, 0.f, 0.f, 0.f};
                        sc[rt * 4 + ck] = MFMA16(Aq, Bk[ck], z);
                    }
                }
            }
            // --- softmax per row (in-wave, 16-lane groups) ---
            const float sscale = 0.17677669529663687f;  // 1/sqrt(32)
            #pragma unroll
            for (int t = 0; t < 16; ++t)
                #pragma unroll
                for (int i = 0; i < 4; ++i) sc[t][i] *= sscale;
            #pragma unroll
            for (int rt = 0; rt < 4; ++rt)
                #pragma unroll
                for (int i = 0; i < 4; ++i) {
                    float m_ = fmaxf(fmaxf(sc[rt * 4 + 0][i], sc[rt * 4 + 1][i]),
                                     fmaxf(sc[rt * 4 + 2][i], sc[rt * 4 + 3][i]));
                    m_ = fmaxf(m_, __shfl_xor(m_, 1));
                    m_ = fmaxf(m_, __shfl_xor(m_, 2));
                    m_ = fmaxf(m_, __shfl_xor(m_, 4));
                    m_ = fmaxf(m_, __shfl_xor(m_, 8));
                    float s_ = 0.f;
                    #pragma unroll
                    for (int ck = 0; ck < 4; ++ck) {
                        sc[rt * 4 + ck][i] = __expf(sc[rt * 4 + ck][i] - m_);
                        s_ += sc[rt * 4 + ck][i];
                    }
                    s_ += __shfl_xor(s_, 1); s_ += __shfl_xor(s_, 2);
                    s_ += __shfl_xor(s_, 4); s_ += __shfl_xor(s_, 8);
                    float inv = 1.f / s_;
                    int row = rt * 16 + quad * 4 + i;
                    #pragma unroll
                    for (int ck = 0; ck < 4; ++ck)
                        PSw[row * 72 + ck * 16 + ln] = f2b(sc[rt * 4 + ck][i] * inv);
                }

            // --- av = P @ V (M=64,N=32,K=64), wave-private ---
            {
                bf16x8 Bv[4];
                #pragma unroll
                for (int ct2 = 0; ct2 < 2; ++ct2)
                    #pragma unroll
                    for (int kt2 = 0; kt2 < 2; ++kt2)
                        Bv[ct2 * 2 + kt2] = *(const bf16x8*)&VTw[(ct2 * 16 + ln) * 72 + kt2 * 32 + quad * 8];
                #pragma unroll
                for (int rt = 0; rt < 4; ++rt) {
                    bf16x8 Ap[2];
                    #pragma unroll
                    for (int kt2 = 0; kt2 < 2; ++kt2)
                        Ap[kt2] = *(const bf16x8*)&PSw[(rt * 16 + ln) * 72 + kt2 * 32 + quad * 8];
                    #pragma unroll
                    for (int ct2 = 0; ct2 < 2; ++ct2) {
                        f32x4 c = {0.f, 0.f, 0.f, 0.f};
                        #pragma unroll
                        for (int kt2 = 0; kt2 < 2; ++kt2) c = MFMA16(Ap[kt2], Bv[ct2 * 2 + kt2], c);
                        avr[hp * 8 + rt * 2 + ct2] = c;
                    }
                }
            }
        }

        __syncthreads();   // all waves done reading hS(h)
        // write av (wave's exact 64-col strip) -> hS
        #pragma unroll
        for (int hp = 0; hp < 2; ++hp)
            #pragma unroll
            for (int rt = 0; rt < 4; ++rt)
                #pragma unroll
                for (int ct2 = 0; ct2 < 2; ++ct2)
                    #pragma unroll
                    for (int i = 0; i < 4; ++i)
                        hS[(rt * 16 + quad * 4 + i) * 264 + nb + hp * 32 + ct2 * 16 + ln]
                            = f2b(avr[hp * 8 + rt * 2 + ct2][i]);
        __syncthreads();

        // ---- O-proj: oacc = h + bo + av @ Wo (K=256) ----
        f32x4 oacc[16];
        #pragma unroll
        for (int rt = 0; rt < 4; ++rt)
            #pragma unroll
            for (int ct = 0; ct < 4; ++ct) {
                float bz = bo_p[nb + ct * 16 + ln];
                f32x4 t = hr[rt * 4 + ct];
                t[0] += bz; t[1] += bz; t[2] += bz; t[3] += bz;
                oacc[rt * 4 + ct] = t;
            }
        {
            bf16x8 Bo[32];
            #pragma unroll
            for (int ct = 0; ct < 4; ++ct)
                #pragma unroll
                for (int kt = 0; kt < 8; ++kt)
                    Bo[ct * 8 + kt] = *(const bf16x8*)(WoE + (size_t)(nb + ct * 16 + ln) * 256 + kt * 32 + quad * 8);
            #pragma unroll
            for (int rt = 0; rt < 4; ++rt) {
                bf16x8 Af[8];
                #pragma unroll
                for (int kt = 0; kt < 8; ++kt)
                    Af[kt] = *(const bf16x8*)&hS[(rt * 16 + ln) * 264 + kt * 32 + quad * 8];
                #pragma unroll
                for (int ct = 0; ct < 4; ++ct)
                    #pragma unroll
                    for (int kt = 0; kt < 8; ++kt)
                        oacc[rt * 4 + ct] = MFMA16(Af[kt], Bo[ct * 8 + kt], oacc[rt * 4 + ct]);
            }
        }

        // ---- LN1 -> hr, hS ----
        LN(oacc, ln1g + el * 256, ln1b + el * 256);

        // ---- FF: 8 chunks of 128 FF cols ----
        f32x4 facc[16];
        {
            const float* b2_p = b2 + el * 256;
            #pragma unroll
            for (int rt = 0; rt < 4; ++rt)
                #pragma unroll
                for (int ct = 0; ct < 4; ++ct) {
                    float bz = b2_p[nb + ct * 16 + ln];
                    f32x4 t = hr[rt * 4 + ct];
                    t[0] += bz; t[1] += bz; t[2] += bz; t[3] += bz;
                    facc[rt * 4 + ct] = t;
                }
        }
        const float* b1_p = b1 + el * 1024;
        for (int ch = 0; ch < 8; ++ch) {
            // W1 slice: wave owns 32 FF cols
            const int fb = ch * 128 + wg * 32;
            {
                bf16x8 B1[16];
                #pragma unroll
                for (int ct2 = 0; ct2 < 2; ++ct2)
                    #pragma unroll
                    for (int kt = 0; kt < 8; ++kt)
                        B1[ct2 * 8 + kt] = *(const bf16x8*)(W1E + (size_t)(fb + ct2 * 16 + ln) * 256 + kt * 32 + quad * 8);
                float bz2[2];
                #pragma unroll
                for (int ct2 = 0; ct2 < 2; ++ct2) bz2[ct2] = b1_p[fb + ct2 * 16 + ln];
                #pragma unroll
                for (int rt = 0; rt < 4; ++rt) {
                    bf16x8 Af[8];
                    #pragma unroll
                    for (int kt = 0; kt < 8; ++kt)
                        Af[kt] = *(const bf16x8*)&hS[(rt * 16 + ln) * 264 + kt * 32 + quad * 8];
                    #pragma unroll
                    for (int ct2 = 0; ct2 < 2; ++ct2) {
                        f32x4 c = {bz2[ct2], bz2[ct2], bz2[ct2], bz2[ct2]};
                        #pragma unroll
                        for (int kt = 0; kt < 8; ++kt) c = MFMA16(Af[kt], B1[ct2 * 8 + kt], c);
                        #pragma unroll
                        for (int i = 0; i < 4; ++i)
                            tS[(rt * 16 + quad * 4 + i) * 136 + wg * 32 + ct2 * 16 + ln]
                                = f2b(fmaxf(c[i], 0.f));
                    }
                }
            }
            __syncthreads();
            // W2 partial: K=128
            {
                bf16x8 B2[16];
                #pragma unroll
                for (int ct = 0; ct < 4; ++ct)
                    #pragma unroll
                    for (int kt2 = 0; kt2 < 4; ++kt2)
                        B2[ct * 4 + kt2] = *(const bf16x8*)(W2E + (size_t)(nb + ct * 16 + ln) * 1024 + ch * 128 + kt2 * 32 + quad * 8);
                #pragma unroll
                for (int rt = 0; rt < 4; ++rt) {
                    bf16x8 At[4];
                    #pragma unroll
                    for (int kt2 = 0; kt2 < 4; ++kt2)
                        At[kt2] = *(const bf16x8*)&tS[(rt * 16 + ln) * 136 + kt2 * 32 + quad * 8];
                    #pragma unroll
                    for (int ct = 0; ct < 4; ++ct)
                        #pragma unroll
                        for (int kt2 = 0; kt2 < 4; ++kt2)
                            facc[rt * 4 + ct] = MFMA16(At[kt2], B2[ct * 4 + kt2], facc[rt * 4 + ct]);
                }
            }
            __syncthreads();
        }

        // ---- LN2 -> hr, hS ----
        LN(facc, ln2g + el * 256, ln2b + el * 256);
    }

    // ---- pooling + Wout + weighted combine ----
    {
        #pragma unroll
        for (int ct = 0; ct < 4; ++ct) {
            float s_ = 0.f;
            #pragma unroll
            for (int rt = 0; rt < 4; ++rt)
                #pragma unroll
                for (int i = 0; i < 4; ++i) s_ += hr[rt * 4 + ct][i];
            s_ += __shfl_xor(s_, 16);
            s_ += __shfl_xor(s_, 32);
            if (quad == 0) pooledS[nb + ct * 16 + ln] = s_ * (1.f / 64.f);
        }
        __syncthreads();
        if (tid < 64) {
            const float* Wout_p = Wout + (size_t)e * (256 * 64);
            float o = bout[e * 64 + tid];
            for (int c = 0; c < 256; ++c) o += pooledS[c] * Wout_p[c * 64 + tid];
            atomicAdd(&acc_out[b * 64 + tid], wgt * o);
        }
    }
}

// ---------------------------------------------------------------------------
__global__ __launch_bounds__(64) void final_ln_kernel(
    const float* __restrict__ acc_out, const float* __restrict__ on_g,
    const float* __restrict__ on_b, float* __restrict__ out)
{
    const int b = blockIdx.x;
    const int d = threadIdx.x;
    float v = acc_out[b * 64 + d];
    float s1 = v, s2 = v * v;
    #pragma unroll
    for (int st = 1; st < 64; st <<= 1) {
        s1 += __shfl_xor(s1, st, 64);
        s2 += __shfl_xor(s2, st, 64);
    }
    float m   = s1 * (1.f / 64.f);
    float var = s2 * (1.f / 64.f) - m * m;
    float rstd = rsqrtf(var + 1e-5f);
    out[b * 64 + d] = (v - m) * rstd * on_g[d] + on_b[d];
}

// ---------------------------------------------------------------------------
extern "C" void kernel_launch(void* const* d_in, const int* in_sizes, int n_in,
                              void* d_out, int out_size, void* d_ws, size_t ws_size,
                              hipStream_t stream)
{
    (void)in_sizes; (void)n_in; (void)out_size; (void)ws_size;
    const float* x    = (const float*)d_in[0];
    const float* Win  = (const float*)d_in[1];
    const float* bin_ = (const float*)d_in[2];
    const float* Wq   = (const float*)d_in[3];
    const float* bq   = (const float*)d_in[4];
    const float* Wk   = (const float*)d_in[5];
    const float* bk   = (const float*)d_in[6];
    const float* Wv   = (const float*)d_in[7];
    const float* bv   = (const float*)d_in[8];
    const float* Wo   = (const float*)d_in[9];
    const float* bo   = (const float*)d_in[10];
    const float* ln1g = (const float*)d_in[11];
    const float* ln1b = (const float*)d_in[12];
    const float* ln2g = (const float*)d_in[13];
    const float* ln2b = (const float*)d_in[14];
    const float* W1   = (const float*)d_in[15];
    const float* b1   = (const float*)d_in[16];
    const float* W2   = (const float*)d_in[17];
    const float* b2   = (const float*)d_in[18];
    const float* Wout = (const float*)d_in[19];
    const float* bout = (const float*)d_in[20];
    const float* Wg   = (const float*)d_in[21];
    const float* bg   = (const float*)d_in[22];
    const float* Wr   = (const float*)d_in[23];
    const float* br   = (const float*)d_in[24];
    const float* on_g = (const float*)d_in[25];
    const float* on_b = (const float*)d_in[26];
    float* out = (float*)d_out;

    // workspace carve-up
    char* ws = (char*)d_ws;
    float* acc_out = (float*)ws;                         // 131,072 B
    int*   cnt     = (int*)(ws + 131072);
    int*   rlist   = (int*)(ws + 131200);                // 16,384 B
    float* wlist   = (float*)(ws + 147584);              // 16,384 B
    short* WinT    = (short*)(ws + 164096);              //   524,288 B
    short* WqT     = (short*)(ws + 688384);              // 2,097,152 B
    short* WkT     = (short*)(ws + 2785536);
    short* WvT     = (short*)(ws + 4882688);
    short* WoT     = (short*)(ws + 6979840);
    short* W1T     = (short*)(ws + 9076992);             // 8,388,608 B
    short* W2T     = (short*)(ws + 17465600);            // 8,388,608 B

    // weight transposition fp32 [R][C] -> bf16 [C][R]
    convT_kernel<<<1024, 256, 0, stream>>>(Win, WinT, 128, 256, 262144);
    convT_kernel<<<4096, 256, 0, stream>>>(Wq, WqT, 256, 256, 1048576);
    convT_kernel<<<4096, 256, 0, stream>>>(Wk, WkT, 256, 256, 1048576);
    convT_kernel<<<4096, 256, 0, stream>>>(Wv, WvT, 256, 256, 1048576);
    convT_kernel<<<4096, 256, 0, stream>>>(Wo, WoT, 256, 256, 1048576);
    convT_kernel<<<16384, 256, 0, stream>>>(W1, W1T, 256, 1024, 4194304);
    convT_kernel<<<16384, 256, 0, stream>>>(W2, W2T, 1024, 256, 4194304);

    zero_cnt_kernel<<<1, 64, 0, stream>>>(cnt);
    gate_kernel<<<512, 256, 0, stream>>>(x, Wg, bg, cnt, rlist, wlist);
    resproj_kernel<<<64, 256, 0, stream>>>(x, Wr, br, acc_out);
    expert_kernel<<<4096, 256, 0, stream>>>(x,
        WinT, bin_, WqT, bq, WkT, bk, WvT, bv, WoT, bo,
        ln1g, ln1b, ln2g, ln2b, W1T, b1, W2T, b2, Wout, bout,
        cnt, rlist, wlist, acc_out);
    final_ln_kernel<<<512, 64, 0, stream>>>(acc_out, on_g, on_b, out);
}